// Round 3
// baseline (486.045 us; speedup 1.0000x reference)
//
#include <hip/hip_runtime.h>
#include <hip/hip_bf16.h>

typedef unsigned short u16;
typedef unsigned int   u32;
typedef __attribute__((ext_vector_type(8))) __bf16 bf16x8;
typedef __attribute__((ext_vector_type(4))) float  f32x4;
typedef __attribute__((ext_vector_type(8))) u16    u16x8;
typedef __attribute__((ext_vector_type(4))) u16    u16x4;

#define S_LEN 2048
#define DMODEL 4096
#define NH 64
#define NKV 4
#define HD 64

__device__ __forceinline__ u16 f2bf(float f) {
  u32 u = __builtin_bit_cast(u32, f);
  u32 r = (u + 0x7FFFu + ((u >> 16) & 1u)) >> 16;
  return (u16)r;
}
__device__ __forceinline__ u16 bfc(float f) {
  return __builtin_bit_cast(u16, (__bf16)f);
}

__device__ __forceinline__ void gll16(const void* g, void* l) {
  __builtin_amdgcn_global_load_lds(
      (__attribute__((address_space(1))) void*)g,
      (__attribute__((address_space(3))) void*)l, 16, 0, 0);
}

// swizzled byte offset within a [rows][8 chunks of 16B] tile (128B row stride)
#define SWZ(row, chunk) (((row) * 128) + ((((chunk) ^ ((row) & 7))) << 4))

// ---------------- elementwise converts ----------------
__global__ __launch_bounds__(256) void cvt_f32_bf16_v4(const float* __restrict__ in,
                                                       u16* __restrict__ out) {
  const int i = blockIdx.x * 256 + threadIdx.x;
  float4 f = ((const float4*)in)[i];
  u16x4 u = { f2bf(f.x), f2bf(f.y), f2bf(f.z), f2bf(f.w) };
  *(u16x4*)&out[(size_t)i * 4] = u;
}

// transpose-convert with row stride: in fp32 R x C (row stride istride) -> out bf16 C x R
__global__ __launch_bounds__(256) void tconvs(const float* __restrict__ in, int istride,
                                              u16* __restrict__ out, int R, int C) {
  __shared__ float tile[32][33];
  const int nc = C >> 5;
  const int cb = blockIdx.x % nc, rb = blockIdx.x / nc;
  const int tx = threadIdx.x & 31, ty = threadIdx.x >> 5;
#pragma unroll
  for (int i = 0; i < 4; ++i)
    tile[ty + i * 8][tx] = in[(size_t)(rb * 32 + ty + i * 8) * istride + cb * 32 + tx];
  __syncthreads();
#pragma unroll
  for (int i = 0; i < 4; ++i)
    out[(size_t)(cb * 32 + ty + i * 8) * R + rb * 32 + tx] = f2bf(tile[tx][ty + i * 8]);
}

// ---------------- RMSNorm + RoPE (one wave = one (s,head) row of 64) ------------
__global__ __launch_bounds__(256) void norm_rope(const float* __restrict__ in, int in_stride,
                                                 int nheads,
                                                 const float* __restrict__ nw,
                                                 const float* __restrict__ cosT,
                                                 const float* __restrict__ sinT,
                                                 u16* __restrict__ outp, int out_stride,
                                                 float oscale) {
  const int wid = blockIdx.x * 4 + (threadIdx.x >> 6);
  const int l = threadIdx.x & 63;
  const int s = wid / nheads, h = wid - s * nheads;
  const float v = in[(size_t)s * in_stride + h * 64 + l];
  float sq = v * v;
#pragma unroll
  for (int off = 32; off; off >>= 1) sq += __shfl_xor(sq, off, 64);
  const float rr = rsqrtf(sq * (1.f / 64.f) + 1e-5f);
  const float vn = v * rr * nw[l];
  const float p = __shfl_xor(vn, 1, 64);
  const int i2 = l >> 1;
  const float c = cosT[(size_t)s * 32 + i2];
  const float sn = sinT[(size_t)s * 32 + i2];
  const float o = ((l & 1) ? fmaf(p, sn, vn * c) : fmaf(-p, sn, vn * c)) * oscale;
  outp[(size_t)s * out_stride + h * 64 + l] = f2bf(o);
}

// ---------------- small GEMM (KV projection): C = A @ Bt^T, 128x128 tiles ------
__global__ __launch_bounds__(256) void gemm_bt(const u16* __restrict__ A,
                                               const u16* __restrict__ Bt,
                                               float* __restrict__ C,
                                               int M, int N, int K) {
  __shared__ __align__(16) u16 As[128 * 32];
  __shared__ __align__(16) u16 Bs[128 * 32];
  int bid = blockIdx.x;
  const int cpx = gridDim.x >> 3;
  bid = (bid & 7) * cpx + (bid >> 3);
  const int nbn = N >> 7;
  const int bm = bid / nbn, bn = bid % nbn;
  const int m0 = bm << 7, n0 = bn << 7;
  const int tid = threadIdx.x;
  const int w = tid >> 6, l = tid & 63;
  const int wr = w >> 1, wc = w & 1;
  f32x4 acc[4][4] = {};

  const char* Ag = (const char*)A + ((size_t)(m0 + w * 32 + (l >> 2)) * K + (l & 3) * 8) * 2;
  const char* Bg = (const char*)Bt + ((size_t)(n0 + w * 32 + (l >> 2)) * K + (l & 3) * 8) * 2;
  char* Al = (char*)As + (w * 32) * 64;
  char* Bl = (char*)Bs + (w * 32) * 64;
  const size_t rowadv = (size_t)16 * K * 2;

  for (int k0 = 0; k0 < K; k0 += 32) {
    gll16(Ag, Al);
    gll16(Ag + rowadv, Al + 1024);
    gll16(Bg, Bl);
    gll16(Bg + rowadv, Bl + 1024);
    Ag += 64; Bg += 64;
    __syncthreads();
    bf16x8 af[4], bq[4];
#pragma unroll
    for (int i = 0; i < 4; ++i) {
      af[i] = *(const bf16x8*)&As[(wr * 64 + i * 16 + (l & 15)) * 32 + (l >> 4) * 8];
      bq[i] = *(const bf16x8*)&Bs[(wc * 64 + i * 16 + (l & 15)) * 32 + (l >> 4) * 8];
    }
#pragma unroll
    for (int mi = 0; mi < 4; ++mi)
#pragma unroll
      for (int ni = 0; ni < 4; ++ni)
        acc[mi][ni] = __builtin_amdgcn_mfma_f32_16x16x32_bf16(af[mi], bq[ni], acc[mi][ni], 0, 0, 0);
    __syncthreads();
  }
  const int r0 = (l >> 4) * 4, c0 = l & 15;
#pragma unroll
  for (int mi = 0; mi < 4; ++mi)
#pragma unroll
    for (int ni = 0; ni < 4; ++ni)
#pragma unroll
      for (int r = 0; r < 4; ++r)
        C[(size_t)(m0 + wr * 64 + mi * 16 + r0 + r) * N + (n0 + wc * 64 + ni * 16 + c0)] =
            acc[mi][ni][r];
}

// ---------------- big GEMM: 256x256 tile, BK=64, 8 waves, pipelined ----------
// LDS (dynamic 128KB): buf[2] of { A: [2 ks][128 R][128B] , B: same } (64KB each).
// Each 128B LDS row packs two global rows' 64B k-slices; 16B slots XOR-swizzled.
__global__ __launch_bounds__(512, 2) void gemm8(const u16* __restrict__ A,
                                                const u16* __restrict__ Bt,
                                                float* __restrict__ C,
                                                int M, int N, int K) {
  extern __shared__ __align__(16) char lds[];
  int bid = blockIdx.x;
  const int cpx = gridDim.x >> 3;
  bid = (bid & 7) * cpx + (bid >> 3);
  const int nbn = N >> 8;
  const int bm = bid / nbn, bn = bid % nbn;
  const int m0 = bm << 8, n0 = bn << 8;
  const int t = threadIdx.x, w = t >> 6, l = t & 63;
  const int wr = w >> 2, wc = w & 3;
  const int lr = l & 15, lg = l >> 4;

  // staging: thread t fills LDS rows R=t>>3 and R+64 of a 16KB chunk, slot t&7
  const int sR = t >> 3, slot = t & 7;
  const int su = slot ^ (sR & 7);                 // inverse-swizzled source piece
  const int d1 = sR * 128 + slot * 16;            // linear LDS offsets
  const int d2 = d1 + 64 * 128;
  const u16* Ag = A + (size_t)(m0 + 2 * sR + (su >> 2)) * K + (su & 3) * 8;
  const u16* Bg = Bt + (size_t)(n0 + 2 * sR + (su >> 2)) * K + (su & 3) * 8;
  const size_t r128 = (size_t)128 * K;

  f32x4 acc[8][4] = {};
  const int nkt = K >> 6;

  auto stage = [&](int kt, int ks, int buf) {
    const int kofs = kt * 64 + ks * 32;
    char* db = lds + buf * 65536 + ks * 16384;
    gll16(Ag + kofs, db + d1);
    gll16(Ag + r128 + kofs, db + d2);
    gll16(Bg + kofs, db + 32768 + d1);
    gll16(Bg + r128 + kofs, db + 32768 + d2);
  };

  // prologue: tile 0 fully staged into buf0 (8 loads in flight)
  stage(0, 0, 0);
  stage(0, 1, 0);

  const int sfrag = ((lr & 1) << 2) | lg;  // unswizzled slot of this lane's fragment

  for (int kt2 = 0; kt2 < nkt; kt2 += 2) {
#pragma unroll
    for (int half = 0; half < 2; ++half) {
      const int kt = kt2 + half;
      const int cur = half;                 // buffer parity == kt parity
      const bool more = (kt + 1 < nkt);
#pragma unroll
      for (int ks = 0; ks < 2; ++ks) {
        if (more || ks == 0)
          asm volatile("s_waitcnt vmcnt(4)" ::: "memory");
        else
          asm volatile("s_waitcnt vmcnt(0)" ::: "memory");
        __builtin_amdgcn_s_barrier();
        asm volatile("" ::: "memory");
        if (more) stage(kt + 1, ks, cur ^ 1);
        const char* base = lds + cur * 65536 + ks * 16384;
        bf16x8 a[8], b[4];
#pragma unroll
        for (int mf = 0; mf < 8; ++mf) {
          const int R = wr * 64 + mf * 8 + (lr >> 1);
          a[mf] = *(const bf16x8*)(base + R * 128 + ((sfrag ^ (R & 7)) << 4));
        }
#pragma unroll
        for (int nf = 0; nf < 4; ++nf) {
          const int R = wc * 32 + nf * 8 + (lr >> 1);
          b[nf] = *(const bf16x8*)(base + 32768 + R * 128 + ((sfrag ^ (R & 7)) << 4));
        }
        __builtin_amdgcn_s_setprio(1);
#pragma unroll
        for (int mf = 0; mf < 8; ++mf)
#pragma unroll
          for (int nf = 0; nf < 4; ++nf)
            acc[mf][nf] = __builtin_amdgcn_mfma_f32_16x16x32_bf16(a[mf], b[nf], acc[mf][nf], 0, 0, 0);
        __builtin_amdgcn_s_setprio(0);
        asm volatile("" ::: "memory");
      }
    }
  }
  // epilogue
#pragma unroll
  for (int mf = 0; mf < 8; ++mf)
#pragma unroll
    for (int nf = 0; nf < 4; ++nf)
#pragma unroll
      for (int rr = 0; rr < 4; ++rr)
        C[(size_t)(m0 + wr * 128 + mf * 16 + lg * 4 + rr) * N +
          (n0 + wc * 64 + nf * 16 + lr)] = acc[mf][nf][rr];
}

// ---------------- flash attention (causal, GQA) ----------------
// Q pre-scaled by 0.125*log2(e); softmax in exp2 domain.
__global__ __launch_bounds__(256) void attn_fwd(const u16* __restrict__ Q,
                                                const u16* __restrict__ Kb,
                                                const u16* __restrict__ VT,
                                                u16* __restrict__ O) {
  const int h = blockIdx.x & 63;
  const int qb = (S_LEN / 64 - 1) - (blockIdx.x >> 6);  // big blocks first
  const int kvh = h >> 4;
  __shared__ __align__(16) u16 Ks[64 * 64];
  __shared__ __align__(16) u16 Vs[64 * 64];
  __shared__ __align__(16) u16 Ps[4 * 16 * 64];
  const int tid = threadIdx.x;
  const int w = tid >> 6, l = tid & 63;
  const int lr = l & 15, lg = l >> 4;

  const int srow = w * 16 + (l >> 3);
  const int slot = l & 7;
  const int sc = slot ^ (srow & 7);
  const char* Kg = (const char*)Kb + kvh * 128 + (size_t)srow * 512 + sc * 16;
  const char* Vg = (const char*)VT + (size_t)(kvh * 64 + srow) * (S_LEN * 2) + sc * 16;
  char* Kl = (char*)Ks + w * 2048;
  char* Vl = (char*)Vs + w * 2048;

  bf16x8 qf[2];
  {
    const size_t qoff = (size_t)(qb * 64 + w * 16 + lr) * DMODEL + h * HD + lg * 8;
    qf[0] = *(const bf16x8*)&Q[qoff];
    qf[1] = *(const bf16x8*)&Q[qoff + 32];
  }
  f32x4 o[4] = {};
  float mrow[4] = {-1e30f, -1e30f, -1e30f, -1e30f};
  float lrow[4] = {0.f, 0.f, 0.f, 0.f};
  const int qrow0 = qb * 64 + w * 16 + lg * 4;

  for (int t = 0; t <= qb; ++t) {
    const int kv0 = t * 64;
    __syncthreads();
    gll16(Kg, Kl);
    gll16(Kg + 8 * 512, Kl + 1024);
    gll16(Vg, Vl);
    gll16(Vg + 8 * (S_LEN * 2), Vl + 1024);
    Kg += 64 * 512;
    Vg += 128;
    __syncthreads();

    f32x4 sf[4] = {};
#pragma unroll
    for (int ni = 0; ni < 4; ++ni) {
      const int row = ni * 16 + lr;
      bf16x8 kf0 = *(const bf16x8*)((const char*)Ks + SWZ(row, lg));
      bf16x8 kf1 = *(const bf16x8*)((const char*)Ks + SWZ(row, 4 + lg));
      sf[ni] = __builtin_amdgcn_mfma_f32_16x16x32_bf16(qf[0], kf0, sf[ni], 0, 0, 0);
      sf[ni] = __builtin_amdgcn_mfma_f32_16x16x32_bf16(qf[1], kf1, sf[ni], 0, 0, 0);
    }
    float mx[4] = {-1e30f, -1e30f, -1e30f, -1e30f};
    if (t == qb) {
#pragma unroll
      for (int ni = 0; ni < 4; ++ni) {
        const int col = kv0 + ni * 16 + lr;
#pragma unroll
        for (int r = 0; r < 4; ++r) {
          float s = sf[ni][r];
          if (col > qrow0 + r) s = -1e30f;
          sf[ni][r] = s;
          mx[r] = fmaxf(mx[r], s);
        }
      }
    } else {
#pragma unroll
      for (int ni = 0; ni < 4; ++ni)
#pragma unroll
        for (int r = 0; r < 4; ++r) mx[r] = fmaxf(mx[r], sf[ni][r]);
    }
#pragma unroll
    for (int r = 0; r < 4; ++r) {
#pragma unroll
      for (int off = 1; off < 16; off <<= 1)
        mx[r] = fmaxf(mx[r], __shfl_xor(mx[r], off, 64));
    }
    float alpha[4], rs[4];
#pragma unroll
    for (int r = 0; r < 4; ++r) {
      float mn = fmaxf(mrow[r], mx[r]);
      alpha[r] = exp2f(mrow[r] - mn);
      mrow[r] = mn;
      rs[r] = 0.f;
    }
#pragma unroll
    for (int ni = 0; ni < 4; ++ni)
#pragma unroll
      for (int r = 0; r < 4; ++r) {
        float p = exp2f(sf[ni][r] - mrow[r]);
        sf[ni][r] = p;
        rs[r] += p;
      }
#pragma unroll
    for (int r = 0; r < 4; ++r) {
#pragma unroll
      for (int off = 1; off < 16; off <<= 1)
        rs[r] += __shfl_xor(rs[r], off, 64);
      lrow[r] = lrow[r] * alpha[r] + rs[r];
      o[0][r] *= alpha[r];
      o[1][r] *= alpha[r];
      o[2][r] *= alpha[r];
      o[3][r] *= alpha[r];
    }
    {
      char* Pw = (char*)Ps + w * 2048;
#pragma unroll
      for (int ni = 0; ni < 4; ++ni) {
        const int chnk = (ni * 16 + lr) >> 3;
        const int sub = (lr & 7) << 1;
#pragma unroll
        for (int r = 0; r < 4; ++r) {
          const int row = lg * 4 + r;
          *(u16*)(Pw + row * 128 + (((chnk ^ (row & 7))) << 4) + sub) = bfc(sf[ni][r]);
        }
      }
    }
#pragma unroll
    for (int kk = 0; kk < 2; ++kk) {
      bf16x8 pa = *(const bf16x8*)((const char*)Ps + w * 2048 + SWZ(lr, kk * 4 + lg));
#pragma unroll
      for (int ni = 0; ni < 4; ++ni) {
        const int row = ni * 16 + lr;
        bf16x8 vf = *(const bf16x8*)((const char*)Vs + SWZ(row, kk * 4 + lg));
        o[ni] = __builtin_amdgcn_mfma_f32_16x16x32_bf16(pa, vf, o[ni], 0, 0, 0);
      }
    }
  }
#pragma unroll
  for (int ni = 0; ni < 4; ++ni)
#pragma unroll
    for (int r = 0; r < 4; ++r) {
      const size_t orow = (size_t)(qb * 64 + w * 16 + lg * 4 + r);
      O[orow * DMODEL + h * HD + ni * 16 + lr] = f2bf(o[ni][r] / lrow[r]);
    }
}

// ---------------- launcher ----------------
extern "C" void kernel_launch(void* const* d_in, const int* in_sizes, int n_in,
                              void* d_out, int out_size, void* d_ws, size_t ws_size,
                              hipStream_t stream) {
  const float* x   = (const float*)d_in[0];
  const float* wq  = (const float*)d_in[1];
  const float* wk  = (const float*)d_in[2];
  const float* wv  = (const float*)d_in[3];
  const float* wo  = (const float*)d_in[4];
  const float* qnw = (const float*)d_in[5];
  const float* knw = (const float*)d_in[6];
  const float* fc  = (const float*)d_in[7];
  const float* fs  = (const float*)d_in[8];
  float* out = (float*)d_out;

  char* ws = (char*)d_ws;
  size_t off = 0;
  auto alloc = [&](size_t bytes) {
    char* p = ws + off;
    off += (bytes + 255) & ~(size_t)255;
    return p;
  };
  u16*   xb   = (u16*)alloc((size_t)S_LEN * DMODEL * 2);
  u16*   wqT  = (u16*)alloc((size_t)DMODEL * DMODEL * 2);
  u16*   wkvT = (u16*)alloc((size_t)512 * DMODEL * 2);
  u16*   woT  = (u16*)alloc((size_t)DMODEL * DMODEL * 2);
  float* KVf  = (float*)alloc((size_t)S_LEN * 512 * 4);
  u16*   Qn   = (u16*)alloc((size_t)S_LEN * DMODEL * 2);
  u16*   Kn   = (u16*)alloc((size_t)S_LEN * 256 * 2);
  u16*   VTb  = (u16*)alloc((size_t)256 * S_LEN * 2);
  u16*   Ob   = (u16*)alloc((size_t)S_LEN * DMODEL * 2);
  float* Qf   = out;  // reuse d_out as fp32 Q scratch (fully overwritten at the end)

  hipFuncSetAttribute((const void*)gemm8, hipFuncAttributeMaxDynamicSharedMemorySize, 131072);

  cvt_f32_bf16_v4<<<(S_LEN * DMODEL / 4) / 256, 256, 0, stream>>>(x, xb);
  tconvs<<<(4096 / 32) * (4096 / 32), 256, 0, stream>>>(wq, 4096, wqT, 4096, 4096);
  tconvs<<<(4096 / 32) * (256 / 32), 256, 0, stream>>>(wk, 256, wkvT, 4096, 256);
  tconvs<<<(4096 / 32) * (256 / 32), 256, 0, stream>>>(wv, 256, wkvT + (size_t)256 * 4096, 4096, 256);
  tconvs<<<(4096 / 32) * (4096 / 32), 256, 0, stream>>>(wo, 4096, woT, 4096, 4096);

  gemm8<<<(2048 / 256) * (4096 / 256), 512, 131072, stream>>>(xb, wqT, Qf, 2048, 4096, 4096);
  gemm_bt<<<(2048 / 128) * (512 / 128), 256, 0, stream>>>(xb, wkvT, KVf, 2048, 512, 4096);

  const float QSCALE = 0.125f * 1.44269504088896340736f;
  norm_rope<<<(S_LEN * NH) / 4, 256, 0, stream>>>(Qf, DMODEL, NH, qnw, fc, fs, Qn, DMODEL, QSCALE);
  norm_rope<<<(S_LEN * NKV) / 4, 256, 0, stream>>>(KVf, 512, NKV, knw, fc, fs, Kn, 256, 1.0f);
  // V^T: in = V half of KVf (2048 x 256, row stride 512) -> VT (256 x 2048 bf16)
  tconvs<<<(2048 / 32) * (256 / 32), 256, 0, stream>>>(KVf + 256, 512, VTb, 2048, 256);

  attn_fwd<<<(S_LEN / 64) * NH, 256, 0, stream>>>(Qn, Kn, VTb, Ob);

  gemm8<<<(2048 / 256) * (4096 / 256), 512, 131072, stream>>>(Ob, woT, out, 2048, 4096, 4096);
}

// Round 4
// 408.502 us; speedup vs baseline: 1.1898x; 1.1898x over previous
//
#include <hip/hip_runtime.h>
#include <hip/hip_bf16.h>

typedef unsigned short u16;
typedef unsigned int   u32;
typedef __attribute__((ext_vector_type(8))) __bf16 bf16x8;
typedef __attribute__((ext_vector_type(4))) float  f32x4;
typedef __attribute__((ext_vector_type(8))) u16    u16x8;
typedef __attribute__((ext_vector_type(4))) u16    u16x4;
typedef __attribute__((ext_vector_type(4))) u32    u32x4;

#define S_LEN 2048
#define DMODEL 4096
#define NH 64
#define NKV 4
#define HD 64

__device__ __forceinline__ u16 f2bf(float f) {
  u32 u = __builtin_bit_cast(u32, f);
  u32 r = (u + 0x7FFFu + ((u >> 16) & 1u)) >> 16;
  return (u16)r;
}
__device__ __forceinline__ u16 bfc(float f) {
  return __builtin_bit_cast(u16, (__bf16)f);
}
__device__ __forceinline__ u32 pk2(float lo, float hi) {
  return (u32)bfc(lo) | ((u32)bfc(hi) << 16);
}

__device__ __forceinline__ void gll16(const void* g, void* l) {
  __builtin_amdgcn_global_load_lds(
      (__attribute__((address_space(1))) void*)g,
      (__attribute__((address_space(3))) void*)l, 16, 0, 0);
}

// swizzled byte offset within a [rows][8 chunks of 16B] tile (128B row stride)
#define SWZ(row, chunk) (((row) * 128) + ((((chunk) ^ ((row) & 7))) << 4))

// ---------------- elementwise converts ----------------
__global__ __launch_bounds__(256) void cvt_f32_bf16_v4(const float* __restrict__ in,
                                                       u16* __restrict__ out) {
  const int i = blockIdx.x * 256 + threadIdx.x;
  float4 f = ((const float4*)in)[i];
  u16x4 u = { f2bf(f.x), f2bf(f.y), f2bf(f.z), f2bf(f.w) };
  *(u16x4*)&out[(size_t)i * 4] = u;
}

// transpose-convert with row stride: in fp32 R x C (row stride istride) -> out bf16 C x R
__global__ __launch_bounds__(256) void tconvs(const float* __restrict__ in, int istride,
                                              u16* __restrict__ out, int R, int C) {
  __shared__ float tile[32][33];
  const int nc = C >> 5;
  const int cb = blockIdx.x % nc, rb = blockIdx.x / nc;
  const int tx = threadIdx.x & 31, ty = threadIdx.x >> 5;
#pragma unroll
  for (int i = 0; i < 4; ++i)
    tile[ty + i * 8][tx] = in[(size_t)(rb * 32 + ty + i * 8) * istride + cb * 32 + tx];
  __syncthreads();
#pragma unroll
  for (int i = 0; i < 4; ++i)
    out[(size_t)(cb * 32 + ty + i * 8) * R + rb * 32 + tx] = f2bf(tile[tx][ty + i * 8]);
}

// ---------------- RMSNorm + RoPE (one wave = one (s,head) row of 64) ------------
__global__ __launch_bounds__(256) void norm_rope(const float* __restrict__ in, int in_stride,
                                                 int nheads,
                                                 const float* __restrict__ nw,
                                                 const float* __restrict__ cosT,
                                                 const float* __restrict__ sinT,
                                                 u16* __restrict__ outp, int out_stride,
                                                 float oscale) {
  const int wid = blockIdx.x * 4 + (threadIdx.x >> 6);
  const int l = threadIdx.x & 63;
  const int s = wid / nheads, h = wid - s * nheads;
  const float v = in[(size_t)s * in_stride + h * 64 + l];
  float sq = v * v;
#pragma unroll
  for (int off = 32; off; off >>= 1) sq += __shfl_xor(sq, off, 64);
  const float rr = rsqrtf(sq * (1.f / 64.f) + 1e-5f);
  const float vn = v * rr * nw[l];
  const float p = __shfl_xor(vn, 1, 64);
  const int i2 = l >> 1;
  const float c = cosT[(size_t)s * 32 + i2];
  const float sn = sinT[(size_t)s * 32 + i2];
  const float o = ((l & 1) ? fmaf(p, sn, vn * c) : fmaf(-p, sn, vn * c)) * oscale;
  outp[(size_t)s * out_stride + h * 64 + l] = f2bf(o);
}

// ---------------- small GEMM (KV projection): C = A @ Bt^T, 128x128 tiles ------
__global__ __launch_bounds__(256) void gemm_bt(const u16* __restrict__ A,
                                               const u16* __restrict__ Bt,
                                               float* __restrict__ C,
                                               int M, int N, int K) {
  __shared__ __align__(16) u16 As[128 * 32];
  __shared__ __align__(16) u16 Bs[128 * 32];
  int bid = blockIdx.x;
  const int cpx = gridDim.x >> 3;
  bid = (bid & 7) * cpx + (bid >> 3);
  const int nbn = N >> 7;
  const int bm = bid / nbn, bn = bid % nbn;
  const int m0 = bm << 7, n0 = bn << 7;
  const int tid = threadIdx.x;
  const int w = tid >> 6, l = tid & 63;
  const int wr = w >> 1, wc = w & 1;
  f32x4 acc[4][4] = {};

  const char* Ag = (const char*)A + ((size_t)(m0 + w * 32 + (l >> 2)) * K + (l & 3) * 8) * 2;
  const char* Bg = (const char*)Bt + ((size_t)(n0 + w * 32 + (l >> 2)) * K + (l & 3) * 8) * 2;
  char* Al = (char*)As + (w * 32) * 64;
  char* Bl = (char*)Bs + (w * 32) * 64;
  const size_t rowadv = (size_t)16 * K * 2;

  for (int k0 = 0; k0 < K; k0 += 32) {
    gll16(Ag, Al);
    gll16(Ag + rowadv, Al + 1024);
    gll16(Bg, Bl);
    gll16(Bg + rowadv, Bl + 1024);
    Ag += 64; Bg += 64;
    __syncthreads();
    bf16x8 af[4], bq[4];
#pragma unroll
    for (int i = 0; i < 4; ++i) {
      af[i] = *(const bf16x8*)&As[(wr * 64 + i * 16 + (l & 15)) * 32 + (l >> 4) * 8];
      bq[i] = *(const bf16x8*)&Bs[(wc * 64 + i * 16 + (l & 15)) * 32 + (l >> 4) * 8];
    }
#pragma unroll
    for (int mi = 0; mi < 4; ++mi)
#pragma unroll
      for (int ni = 0; ni < 4; ++ni)
        acc[mi][ni] = __builtin_amdgcn_mfma_f32_16x16x32_bf16(af[mi], bq[ni], acc[mi][ni], 0, 0, 0);
    __syncthreads();
  }
  const int r0 = (l >> 4) * 4, c0 = l & 15;
#pragma unroll
  for (int mi = 0; mi < 4; ++mi)
#pragma unroll
    for (int ni = 0; ni < 4; ++ni)
#pragma unroll
      for (int r = 0; r < 4; ++r)
        C[(size_t)(m0 + wr * 64 + mi * 16 + r0 + r) * N + (n0 + wc * 64 + ni * 16 + c0)] =
            acc[mi][ni][r];
}

// ---------------- big GEMM: 128x256 tile, BK=64, 8 waves, counted-vmcnt pipeline
// LDS (dynamic 96KB): buf[2] x ks[2] x { A: 8KB (64 rows x 128B) | B: 16KB (128 rows) }
// Each 128B LDS row packs two global rows' 32-k (64B) slices; 16B slots XOR-swizzled.
__global__ __launch_bounds__(512, 2) void gemm8(const u16* __restrict__ A,
                                                const u16* __restrict__ Bt,
                                                float* __restrict__ C,
                                                int M, int N, int K) {
  extern __shared__ __align__(16) char lds[];
  int bid = blockIdx.x;
  const int cpx = gridDim.x >> 3;
  bid = (bid & 7) * cpx + (bid >> 3);
  const int nbn = N >> 8;
  const int bm = bid / nbn, bn = bid % nbn;
  const int m0 = bm << 7, n0 = bn << 8;           // tile 128(M) x 256(N)
  const int t = threadIdx.x, w = t >> 6, l = t & 63;
  const int wr = w >> 2, wc = w & 3;              // waves: 2(M) x 4(N), each 64x64
  const int lr = l & 15, lg = l >> 4;

  // staging: thread t -> LDS row sR=t>>3, slot t&7 (linear dest); source inverse-swizzled
  const int sR = t >> 3, slot = t & 7;
  const int su = slot ^ (sR & 7);
  const int d1 = sR * 128 + slot * 16;
  const u16* Ag = A + (size_t)(m0 + 2 * sR + (su >> 2)) * K + (su & 3) * 8;
  const u16* Bg = Bt + (size_t)(n0 + 2 * sR + (su >> 2)) * K + (su & 3) * 8;
  const size_t r128 = (size_t)128 * K;

  f32x4 acc[4][4] = {};
  const int nkt = K >> 6;
  const int NPH = nkt * 2;

  auto stage = [&](int ph) {
    const int kofs = ph * 32;                      // = kt*64 + ks*32
    char* db = lds + ((ph >> 1) & 1) * 49152 + (ph & 1) * 24576;
    gll16(Ag + kofs, db + d1);                     // A 8KB
    gll16(Bg + kofs, db + 8192 + d1);              // B rows 0..127 (n 0..127)
    gll16(Bg + r128 + kofs, db + 16384 + d1);      // B rows 128..255
  };
  stage(0);
  stage(1);
  const int sfrag = ((lr & 1) << 2) | lg;

#pragma unroll 4
  for (int ph = 0; ph < NPH; ++ph) {
    if (ph < NPH - 1)
      asm volatile("s_waitcnt vmcnt(3)" ::: "memory");
    else
      asm volatile("s_waitcnt vmcnt(0)" ::: "memory");
    __builtin_amdgcn_s_barrier();
    if (ph + 2 < NPH) stage(ph + 2);
    const char* base = lds + ((ph >> 1) & 1) * 49152 + (ph & 1) * 24576;
    bf16x8 a[4], b[4];
#pragma unroll
    for (int mf = 0; mf < 4; ++mf) {
      const int R = (wr * 64 + mf * 16 + lr) >> 1;
      a[mf] = *(const bf16x8*)(base + R * 128 + ((sfrag ^ (R & 7)) << 4));
    }
#pragma unroll
    for (int nf = 0; nf < 4; ++nf) {
      const int R = (wc * 64 + nf * 16 + lr) >> 1;
      b[nf] = *(const bf16x8*)(base + 8192 + R * 128 + ((sfrag ^ (R & 7)) << 4));
    }
    __builtin_amdgcn_s_setprio(1);
#pragma unroll
    for (int mf = 0; mf < 4; ++mf)
#pragma unroll
      for (int nf = 0; nf < 4; ++nf)
        acc[mf][nf] = __builtin_amdgcn_mfma_f32_16x16x32_bf16(a[mf], b[nf], acc[mf][nf], 0, 0, 0);
    __builtin_amdgcn_s_setprio(0);
    asm volatile("" ::: "memory");
  }
#pragma unroll
  for (int mf = 0; mf < 4; ++mf)
#pragma unroll
    for (int nf = 0; nf < 4; ++nf)
#pragma unroll
      for (int rr = 0; rr < 4; ++rr)
        C[(size_t)(m0 + wr * 64 + mf * 16 + lg * 4 + rr) * N +
          (n0 + wc * 64 + nf * 16 + lr)] = acc[mf][nf][rr];
}

// ---------------- flash attention (causal, GQA), swapped-QK^T, in-register P ----
// S^T = K @ Q^T per tile: lane owns all 16 scores of q = lr. Softmax fully in-lane
// (+2 xor shuffles). P->A-fragments via bf16 packs + xor16 exchange; V chunk-permuted
// at staging so each (kk,lg) k-slot group matches its pack source. No P LDS buffer.
__global__ __launch_bounds__(256) void attn_fwd(const u16* __restrict__ Q,
                                                const u16* __restrict__ Kb,
                                                const u16* __restrict__ VT,
                                                u16* __restrict__ O) {
  const int h = blockIdx.x & 63;
  const int qb = (S_LEN / 64 - 1) - (blockIdx.x >> 6);  // big blocks first
  const int kvh = h >> 4;
  __shared__ __align__(16) u16 Ks[64 * 64];
  __shared__ __align__(16) u16 Vs[64 * 64];
  const int tid = threadIdx.x;
  const int w = tid >> 6, l = tid & 63;
  const int lr = l & 15, lg = l >> 4;

  const int srow = w * 16 + (l >> 3);
  const int s0 = (l & 7) ^ (srow & 7);                       // inverse bank swizzle
  const int sv = (s0 & 4) | ((s0 & 1) << 1) | ((s0 & 2) >> 1);  // + pi for V blocks
  const char* Kg = (const char*)Kb + kvh * 128 + (size_t)srow * 512 + s0 * 16;
  const char* Vg = (const char*)VT + (size_t)(kvh * 64 + srow) * (S_LEN * 2) + sv * 16;
  char* Kl = (char*)Ks + w * 2048;
  char* Vl = (char*)Vs + w * 2048;

  bf16x8 qf[2];
  {
    const size_t qoff = (size_t)(qb * 64 + w * 16 + lr) * DMODEL + h * HD + lg * 8;
    qf[0] = *(const bf16x8*)&Q[qoff];
    qf[1] = *(const bf16x8*)&Q[qoff + 32];
  }
  f32x4 o[4] = {};
  float mrow = -1e30f, lrow = 0.f;
  const int qlane = qb * 64 + w * 16 + lr;          // this lane's softmax q-row
  const int abase = (l & 48) | ((l >> 2) & 12);     // lane holding q = lg*4+r is abase+r

  for (int t = 0; t <= qb; ++t) {
    __syncthreads();
    gll16(Kg, Kl);
    gll16(Kg + 8 * 512, Kl + 1024);
    gll16(Vg, Vl);
    gll16(Vg + 8 * (S_LEN * 2), Vl + 1024);
    Kg += 64 * 512;
    Vg += 128;
    __syncthreads();

    // S^T = K @ Q^T : lane holds S[q=lr][kv = kv0 + ni*16 + lg*4 + r]
    f32x4 sf[4] = {};
#pragma unroll
    for (int ni = 0; ni < 4; ++ni) {
      const int row = ni * 16 + lr;
      bf16x8 kf0 = *(const bf16x8*)((const char*)Ks + SWZ(row, lg));
      bf16x8 kf1 = *(const bf16x8*)((const char*)Ks + SWZ(row, 4 + lg));
      sf[ni] = __builtin_amdgcn_mfma_f32_16x16x32_bf16(kf0, qf[0], sf[ni], 0, 0, 0);
      sf[ni] = __builtin_amdgcn_mfma_f32_16x16x32_bf16(kf1, qf[1], sf[ni], 0, 0, 0);
    }
    if (t == qb) {
      const int kvb = t * 64 + lg * 4;
#pragma unroll
      for (int ni = 0; ni < 4; ++ni)
#pragma unroll
        for (int r = 0; r < 4; ++r)
          if (kvb + ni * 16 + r > qlane) sf[ni][r] = -1e30f;
    }
    float mt = -1e30f;
#pragma unroll
    for (int ni = 0; ni < 4; ++ni)
#pragma unroll
      for (int r = 0; r < 4; ++r) mt = fmaxf(mt, sf[ni][r]);
    mt = fmaxf(mt, __shfl_xor(mt, 16, 64));
    mt = fmaxf(mt, __shfl_xor(mt, 32, 64));
    const float mn = fmaxf(mrow, mt);
    const float alpha = exp2f(mrow - mn);
    mrow = mn;
    float p[4][4];
    float rs = 0.f;
#pragma unroll
    for (int ni = 0; ni < 4; ++ni)
#pragma unroll
      for (int r = 0; r < 4; ++r) {
        const float e = exp2f(sf[ni][r] - mn);
        p[ni][r] = e;
        rs += e;
      }
    rs += __shfl_xor(rs, 16, 64);
    rs += __shfl_xor(rs, 32, 64);
    lrow = lrow * alpha + rs;
    const float av0 = __shfl(alpha, abase + 0, 64);
    const float av1 = __shfl(alpha, abase + 1, 64);
    const float av2 = __shfl(alpha, abase + 2, 64);
    const float av3 = __shfl(alpha, abase + 3, 64);
#pragma unroll
    for (int ni = 0; ni < 4; ++ni) {
      o[ni][0] *= av0; o[ni][1] *= av1; o[ni][2] *= av2; o[ni][3] *= av3;
    }
    // O += P @ V : build A-fragments in-register (packs + xor16 exchange)
    const bool odd = (lg & 1);
#pragma unroll
    for (int kk = 0; kk < 2; ++kk) {
      const int nA = 2 * kk, nB = 2 * kk + 1;
      const u32 cA0 = pk2(p[nA][0], p[nA][1]), cA1 = pk2(p[nA][2], p[nA][3]);
      const u32 cB0 = pk2(p[nB][0], p[nB][1]), cB1 = pk2(p[nB][2], p[nB][3]);
      const u32 cS0 = odd ? cB0 : cA0, cS1 = odd ? cB1 : cA1;
      const u32 cP0 = odd ? cA0 : cB0, cP1 = odd ? cA1 : cB1;
      const u32 rP0 = (u32)__shfl_xor((int)cP0, 16, 64);
      const u32 rP1 = (u32)__shfl_xor((int)cP1, 16, 64);
      u32x4 wv;
      wv[0] = odd ? rP0 : cS0;
      wv[1] = odd ? rP1 : cS1;
      wv[2] = odd ? cS0 : rP0;
      wv[3] = odd ? cS1 : rP1;
      const bf16x8 pa = __builtin_bit_cast(bf16x8, wv);
#pragma unroll
      for (int ni = 0; ni < 4; ++ni) {
        const int row = ni * 16 + lr;
        bf16x8 vf = *(const bf16x8*)((const char*)Vs + SWZ(row, kk * 4 + lg));
        o[ni] = __builtin_amdgcn_mfma_f32_16x16x32_bf16(pa, vf, o[ni], 0, 0, 0);
      }
    }
  }
  const float lv0 = __shfl(lrow, abase + 0, 64);
  const float lv1 = __shfl(lrow, abase + 1, 64);
  const float lv2 = __shfl(lrow, abase + 2, 64);
  const float lv3 = __shfl(lrow, abase + 3, 64);
  const f32x4 lv = {lv0, lv1, lv2, lv3};
#pragma unroll
  for (int ni = 0; ni < 4; ++ni)
#pragma unroll
    for (int r = 0; r < 4; ++r) {
      const size_t orow = (size_t)(qb * 64 + w * 16 + lg * 4 + r);
      O[orow * DMODEL + h * HD + ni * 16 + lr] = f2bf(o[ni][r] / lv[r]);
    }
}

// ---------------- launcher ----------------
extern "C" void kernel_launch(void* const* d_in, const int* in_sizes, int n_in,
                              void* d_out, int out_size, void* d_ws, size_t ws_size,
                              hipStream_t stream) {
  const float* x   = (const float*)d_in[0];
  const float* wq  = (const float*)d_in[1];
  const float* wk  = (const float*)d_in[2];
  const float* wv  = (const float*)d_in[3];
  const float* wo  = (const float*)d_in[4];
  const float* qnw = (const float*)d_in[5];
  const float* knw = (const float*)d_in[6];
  const float* fc  = (const float*)d_in[7];
  const float* fs  = (const float*)d_in[8];
  float* out = (float*)d_out;

  char* ws = (char*)d_ws;
  size_t off = 0;
  auto alloc = [&](size_t bytes) {
    char* p = ws + off;
    off += (bytes + 255) & ~(size_t)255;
    return p;
  };
  u16*   xb   = (u16*)alloc((size_t)S_LEN * DMODEL * 2);
  u16*   wqT  = (u16*)alloc((size_t)DMODEL * DMODEL * 2);
  u16*   wkvT = (u16*)alloc((size_t)512 * DMODEL * 2);
  u16*   woT  = (u16*)alloc((size_t)DMODEL * DMODEL * 2);
  float* KVf  = (float*)alloc((size_t)S_LEN * 512 * 4);
  u16*   Qn   = (u16*)alloc((size_t)S_LEN * DMODEL * 2);
  u16*   Kn   = (u16*)alloc((size_t)S_LEN * 256 * 2);
  u16*   VTb  = (u16*)alloc((size_t)256 * S_LEN * 2);
  u16*   Ob   = (u16*)alloc((size_t)S_LEN * DMODEL * 2);
  float* Qf   = out;  // reuse d_out as fp32 Q scratch (fully overwritten at the end)

  hipFuncSetAttribute((const void*)gemm8, hipFuncAttributeMaxDynamicSharedMemorySize, 131072);

  cvt_f32_bf16_v4<<<(S_LEN * DMODEL / 4) / 256, 256, 0, stream>>>(x, xb);
  tconvs<<<(4096 / 32) * (4096 / 32), 256, 0, stream>>>(wq, 4096, wqT, 4096, 4096);
  tconvs<<<(4096 / 32) * (256 / 32), 256, 0, stream>>>(wk, 256, wkvT, 4096, 256);
  tconvs<<<(4096 / 32) * (256 / 32), 256, 0, stream>>>(wv, 256, wkvT + (size_t)256 * 4096, 4096, 256);
  tconvs<<<(4096 / 32) * (4096 / 32), 256, 0, stream>>>(wo, 4096, woT, 4096, 4096);

  gemm8<<<(2048 / 128) * (4096 / 256), 512, 98304, stream>>>(xb, wqT, Qf, 2048, 4096, 4096);
  gemm_bt<<<(2048 / 128) * (512 / 128), 256, 0, stream>>>(xb, wkvT, KVf, 2048, 512, 4096);

  const float QSCALE = 0.125f * 1.44269504088896340736f;
  norm_rope<<<(S_LEN * NH) / 4, 256, 0, stream>>>(Qf, DMODEL, NH, qnw, fc, fs, Qn, DMODEL, QSCALE);
  norm_rope<<<(S_LEN * NKV) / 4, 256, 0, stream>>>(KVf, 512, NKV, knw, fc, fs, Kn, 256, 1.0f);
  // V^T: in = V half of KVf (2048 x 256, row stride 512) -> VT (256 x 2048 bf16)
  tconvs<<<(2048 / 32) * (256 / 32), 256, 0, stream>>>(KVf + 256, 512, VTb, 2048, 256);

  attn_fwd<<<(S_LEN / 64) * NH, 256, 0, stream>>>(Qn, Kn, VTb, Ob);

  gemm8<<<(2048 / 128) * (4096 / 256), 512, 98304, stream>>>(Ob, woT, out, 2048, 4096, 4096);
}

// Round 5
// 372.963 us; speedup vs baseline: 1.3032x; 1.0953x over previous
//
#include <hip/hip_runtime.h>
#include <hip/hip_bf16.h>

typedef unsigned short u16;
typedef unsigned int   u32;
typedef __attribute__((ext_vector_type(8))) __bf16 bf16x8;
typedef __attribute__((ext_vector_type(4))) float  f32x4;
typedef __attribute__((ext_vector_type(8))) u16    u16x8;
typedef __attribute__((ext_vector_type(4))) u16    u16x4;
typedef __attribute__((ext_vector_type(4))) u32    u32x4;

#define S_LEN 2048
#define DMODEL 4096
#define NH 64
#define NKV 4
#define HD 64

__device__ __forceinline__ u16 f2bf(float f) {
  u32 u = __builtin_bit_cast(u32, f);
  u32 r = (u + 0x7FFFu + ((u >> 16) & 1u)) >> 16;
  return (u16)r;
}
__device__ __forceinline__ u16 bfc(float f) {
  return __builtin_bit_cast(u16, (__bf16)f);
}
__device__ __forceinline__ u32 pk2(float lo, float hi) {
  return (u32)bfc(lo) | ((u32)bfc(hi) << 16);
}

__device__ __forceinline__ void gll16(const void* g, void* l) {
  __builtin_amdgcn_global_load_lds(
      (__attribute__((address_space(1))) void*)g,
      (__attribute__((address_space(3))) void*)l, 16, 0, 0);
}

// swizzled byte offset within a [rows][8 chunks of 16B] tile (128B row stride)
#define SWZ(row, chunk) (((row) * 128) + ((((chunk) ^ ((row) & 7))) << 4))

// ---------------- elementwise converts ----------------
__global__ __launch_bounds__(256) void cvt_f32_bf16_v4(const float* __restrict__ in,
                                                       u16* __restrict__ out) {
  const int i = blockIdx.x * 256 + threadIdx.x;
  float4 f = ((const float4*)in)[i];
  u16x4 u = { f2bf(f.x), f2bf(f.y), f2bf(f.z), f2bf(f.w) };
  *(u16x4*)&out[(size_t)i * 4] = u;
}

// out[i] += addend[i], float4
__global__ __launch_bounds__(256) void addv4(float* __restrict__ out,
                                             const float* __restrict__ addend) {
  const int i = blockIdx.x * 256 + threadIdx.x;
  float4 a = ((const float4*)addend)[i];
  float4 o = ((float4*)out)[i];
  o.x += a.x; o.y += a.y; o.z += a.z; o.w += a.w;
  ((float4*)out)[i] = o;
}

// transpose-convert (optionally summing two fp32 srcs): in R x C (row stride istride)
// -> out bf16 C x R
__global__ __launch_bounds__(256) void tconvs(const float* __restrict__ in,
                                              const float* __restrict__ in2, int istride,
                                              u16* __restrict__ out, int R, int C) {
  __shared__ float tile[32][33];
  const int nc = C >> 5;
  const int cb = blockIdx.x % nc, rb = blockIdx.x / nc;
  const int tx = threadIdx.x & 31, ty = threadIdx.x >> 5;
#pragma unroll
  for (int i = 0; i < 4; ++i) {
    const size_t idx = (size_t)(rb * 32 + ty + i * 8) * istride + cb * 32 + tx;
    float v = in[idx];
    if (in2) v += in2[idx];
    tile[ty + i * 8][tx] = v;
  }
  __syncthreads();
#pragma unroll
  for (int i = 0; i < 4; ++i)
    out[(size_t)(cb * 32 + ty + i * 8) * R + rb * 32 + tx] = f2bf(tile[tx][ty + i * 8]);
}

// ---------------- RMSNorm + RoPE (one wave = one (s,head) row of 64) ------------
// reads in[idx] + in2[idx] (split-K partials)
__global__ __launch_bounds__(256) void norm_rope(const float* __restrict__ in,
                                                 const float* __restrict__ in2,
                                                 int in_stride, int nheads,
                                                 const float* __restrict__ nw,
                                                 const float* __restrict__ cosT,
                                                 const float* __restrict__ sinT,
                                                 u16* __restrict__ outp, int out_stride,
                                                 float oscale) {
  const int wid = blockIdx.x * 4 + (threadIdx.x >> 6);
  const int l = threadIdx.x & 63;
  const int s = wid / nheads, h = wid - s * nheads;
  const size_t idx = (size_t)s * in_stride + h * 64 + l;
  const float v = in[idx] + in2[idx];
  float sq = v * v;
#pragma unroll
  for (int off = 32; off; off >>= 1) sq += __shfl_xor(sq, off, 64);
  const float rr = rsqrtf(sq * (1.f / 64.f) + 1e-5f);
  const float vn = v * rr * nw[l];
  const float p = __shfl_xor(vn, 1, 64);
  const int i2 = l >> 1;
  const float c = cosT[(size_t)s * 32 + i2];
  const float sn = sinT[(size_t)s * 32 + i2];
  const float o = ((l & 1) ? fmaf(p, sn, vn * c) : fmaf(-p, sn, vn * c)) * oscale;
  outp[(size_t)s * out_stride + h * 64 + l] = f2bf(o);
}

// ---------------- big GEMM: 256x256 tile, split-K=2, 8 waves (2Mx4N, 128x64/wave)
// LDS 128KB = 4 pages x 32KB; page = 32-k slice { A 16KB | B 16KB }, counted vmcnt.
// Each 128B LDS row packs two global rows' 32-k (64B) slices; 16B slots XOR-swizzled.
__global__ __launch_bounds__(512, 2) void gemm8(const u16* __restrict__ A,
                                                const u16* __restrict__ Bt,
                                                float* __restrict__ C0,
                                                float* __restrict__ C1,
                                                int M, int N, int K) {
  extern __shared__ __align__(16) char lds[];
  const int nbm = M >> 8, nbn = N >> 8;
  int bid = blockIdx.x;
  const int cpx = gridDim.x >> 3;
  bid = (bid & 7) * cpx + (bid >> 3);
  const int pertile = nbm * nbn;
  const int sl = bid / pertile;
  const int rem = bid - sl * pertile;
  const int bm = rem / nbn, bn = rem % nbn;
  const int m0 = bm << 8, n0 = bn << 8;
  const int t = threadIdx.x, w = t >> 6, l = t & 63;
  const int wr = w >> 2, wc = w & 3;            // waves 2(M) x 4(N); per-wave 128x64
  const int lr = l & 15, lg = l >> 4;

  const int Khalf = K >> 1;
  const int kbase = sl * Khalf;

  // staging: thread t -> LDS rows sR / sR+64 (A and B), slot t&7 (linear dest)
  const int sR = t >> 3, slot = t & 7;
  const int su = slot ^ (sR & 7);
  const int d1 = sR * 128 + slot * 16;
  const u16* Ag = A + (size_t)(m0 + 2 * sR + (su >> 2)) * K + kbase + (su & 3) * 8;
  const u16* Bg = Bt + (size_t)(n0 + 2 * sR + (su >> 2)) * K + kbase + (su & 3) * 8;
  const size_t r128 = (size_t)128 * K;

  f32x4 acc[8][4] = {};
  const int NPH = Khalf >> 5;

  auto stage = [&](int ph) {
    const int kofs = ph * 32;
    char* pb = lds + (ph & 3) * 32768;
    gll16(Ag + kofs, pb + d1);
    gll16(Ag + r128 + kofs, pb + 8192 + d1);
    gll16(Bg + kofs, pb + 16384 + d1);
    gll16(Bg + r128 + kofs, pb + 24576 + d1);
  };
  stage(0);
  stage(1);

  const int sfrag = ((lr & 1) << 2) | lg;
  const int swz = (sfrag ^ ((lr >> 1) & 7)) << 4;
  const int aoff = (wr * 64 + (lr >> 1)) * 128 + swz;
  const int boff = 16384 + (wc * 32 + (lr >> 1)) * 128 + swz;

  auto compute = [&](int ph) {
    const char* base = lds + (ph & 3) * 32768;
    bf16x8 a[8], b[4];
#pragma unroll
    for (int mf = 0; mf < 8; ++mf) a[mf] = *(const bf16x8*)(base + aoff + mf * 1024);
#pragma unroll
    for (int nf = 0; nf < 4; ++nf) b[nf] = *(const bf16x8*)(base + boff + nf * 1024);
    __builtin_amdgcn_s_setprio(1);
#pragma unroll
    for (int mf = 0; mf < 8; ++mf)
#pragma unroll
      for (int nf = 0; nf < 4; ++nf)
        acc[mf][nf] = __builtin_amdgcn_mfma_f32_16x16x32_bf16(a[mf], b[nf], acc[mf][nf], 0, 0, 0);
    __builtin_amdgcn_s_setprio(0);
    asm volatile("" ::: "memory");
  };

#pragma unroll 4
  for (int ph = 0; ph < NPH - 2; ++ph) {
    __builtin_amdgcn_sched_barrier(0);
    asm volatile("s_waitcnt vmcnt(4)" ::: "memory");
    __builtin_amdgcn_s_barrier();
    stage(ph + 2);
    compute(ph);
  }
  __builtin_amdgcn_sched_barrier(0);
  asm volatile("s_waitcnt vmcnt(4)" ::: "memory");
  __builtin_amdgcn_s_barrier();
  compute(NPH - 2);
  __builtin_amdgcn_sched_barrier(0);
  asm volatile("s_waitcnt vmcnt(0)" ::: "memory");
  __builtin_amdgcn_s_barrier();
  compute(NPH - 1);

  float* Cs = sl ? C1 : C0;
#pragma unroll
  for (int mf = 0; mf < 8; ++mf)
#pragma unroll
    for (int nf = 0; nf < 4; ++nf)
#pragma unroll
      for (int rr = 0; rr < 4; ++rr)
        Cs[(size_t)(m0 + wr * 128 + mf * 16 + lg * 4 + rr) * N +
           (n0 + wc * 64 + nf * 16 + lr)] = acc[mf][nf][rr];
}

// ---------------- flash attention (causal, GQA), swapped-QK^T, in-register P ----
// Double-buffered K/V staging (raw barrier + vmcnt(0)), defer-rescale (THR=8 in
// exp2 domain). Q pre-scaled by 0.125*log2(e).
__global__ __launch_bounds__(256) void attn_fwd(const u16* __restrict__ Q,
                                                const u16* __restrict__ Kb,
                                                const u16* __restrict__ VT,
                                                u16* __restrict__ O) {
  const int h = blockIdx.x & 63;
  const int qb = (S_LEN / 64 - 1) - (blockIdx.x >> 6);  // big blocks first
  const int kvh = h >> 4;
  __shared__ __align__(16) char KV[2 * 16384];  // page: K 8KB | V 8KB
  const int tid = threadIdx.x;
  const int w = tid >> 6, l = tid & 63;
  const int lr = l & 15, lg = l >> 4;

  const int srow = w * 16 + (l >> 3);
  const int s0 = (l & 7) ^ (srow & 7);                          // inverse bank swizzle
  const int sv = (s0 & 4) | ((s0 & 1) << 1) | ((s0 & 2) >> 1);  // + pi for V packs
  const char* Kg = (const char*)Kb + kvh * 128 + (size_t)srow * 512 + s0 * 16;
  const char* Vg = (const char*)VT + (size_t)(kvh * 64 + srow) * (S_LEN * 2) + sv * 16;
  const int wofs = w * 2048;

  auto stage = [&](int page) {
    char* pb = KV + page * 16384 + wofs;
    gll16(Kg, pb);
    gll16(Kg + 8 * 512, pb + 1024);
    gll16(Vg, pb + 8192);
    gll16(Vg + 8 * (S_LEN * 2), pb + 8192 + 1024);
    Kg += 64 * 512;
    Vg += 128;
  };

  bf16x8 qf[2];
  {
    const size_t qoff = (size_t)(qb * 64 + w * 16 + lr) * DMODEL + h * HD + lg * 8;
    qf[0] = *(const bf16x8*)&Q[qoff];
    qf[1] = *(const bf16x8*)&Q[qoff + 32];
  }
  f32x4 o[4] = {};
  float mrow = -1e30f, lrow = 0.f;
  const int qlane = qb * 64 + w * 16 + lr;          // this lane's softmax q-row
  const int abase = (l & 48) | ((l >> 2) & 12);     // lane holding q = lg*4+r is abase+r

  stage(0);

  for (int t = 0; t <= qb; ++t) {
    __builtin_amdgcn_sched_barrier(0);
    asm volatile("s_waitcnt vmcnt(0)" ::: "memory");
    __builtin_amdgcn_s_barrier();
    __builtin_amdgcn_sched_barrier(0);
    if (t < qb) stage((t + 1) & 1);
    const char* Kp = KV + (t & 1) * 16384;
    const char* Vp = Kp + 8192;

    // S^T = K @ Q^T : lane holds S[q=lr][kv = t*64 + ni*16 + lg*4 + r]
    f32x4 sf[4] = {};
#pragma unroll
    for (int ni = 0; ni < 4; ++ni) {
      const int row = ni * 16 + lr;
      bf16x8 kf0 = *(const bf16x8*)(Kp + SWZ(row, lg));
      bf16x8 kf1 = *(const bf16x8*)(Kp + SWZ(row, 4 + lg));
      sf[ni] = __builtin_amdgcn_mfma_f32_16x16x32_bf16(kf0, qf[0], sf[ni], 0, 0, 0);
      sf[ni] = __builtin_amdgcn_mfma_f32_16x16x32_bf16(kf1, qf[1], sf[ni], 0, 0, 0);
    }
    if (t == qb) {
      const int kvb = t * 64 + lg * 4;
#pragma unroll
      for (int ni = 0; ni < 4; ++ni)
#pragma unroll
        for (int r = 0; r < 4; ++r)
          if (kvb + ni * 16 + r > qlane) sf[ni][r] = -1e30f;
    }
    float mt = -1e30f;
#pragma unroll
    for (int ni = 0; ni < 4; ++ni)
#pragma unroll
      for (int r = 0; r < 4; ++r) mt = fmaxf(mt, sf[ni][r]);
    mt = fmaxf(mt, __shfl_xor(mt, 16, 64));
    mt = fmaxf(mt, __shfl_xor(mt, 32, 64));

    if (__any(mt > mrow + 8.f)) {        // rescale only when the max really grows
      const float mn = fmaxf(mrow, mt);
      const float alpha = exp2f(mrow - mn);
      mrow = mn;
      lrow *= alpha;
      const float av0 = __shfl(alpha, abase + 0, 64);
      const float av1 = __shfl(alpha, abase + 1, 64);
      const float av2 = __shfl(alpha, abase + 2, 64);
      const float av3 = __shfl(alpha, abase + 3, 64);
#pragma unroll
      for (int ni = 0; ni < 4; ++ni) {
        o[ni][0] *= av0; o[ni][1] *= av1; o[ni][2] *= av2; o[ni][3] *= av3;
      }
    }
    float p[4][4];
    float rs = 0.f;
#pragma unroll
    for (int ni = 0; ni < 4; ++ni)
#pragma unroll
      for (int r = 0; r < 4; ++r) {
        const float e = exp2f(sf[ni][r] - mrow);
        p[ni][r] = e;
        rs += e;
      }
    rs += __shfl_xor(rs, 16, 64);
    rs += __shfl_xor(rs, 32, 64);
    lrow += rs;

    // O += P @ V : build A-fragments in-register (packs + xor16 exchange)
    const bool odd = (lg & 1);
#pragma unroll
    for (int kk = 0; kk < 2; ++kk) {
      const int nA = 2 * kk, nB = 2 * kk + 1;
      const u32 cA0 = pk2(p[nA][0], p[nA][1]), cA1 = pk2(p[nA][2], p[nA][3]);
      const u32 cB0 = pk2(p[nB][0], p[nB][1]), cB1 = pk2(p[nB][2], p[nB][3]);
      const u32 cS0 = odd ? cB0 : cA0, cS1 = odd ? cB1 : cA1;
      const u32 cP0 = odd ? cA0 : cB0, cP1 = odd ? cA1 : cB1;
      const u32 rP0 = (u32)__shfl_xor((int)cP0, 16, 64);
      const u32 rP1 = (u32)__shfl_xor((int)cP1, 16, 64);
      u32x4 wv;
      wv[0] = odd ? rP0 : cS0;
      wv[1] = odd ? rP1 : cS1;
      wv[2] = odd ? cS0 : rP0;
      wv[3] = odd ? cS1 : rP1;
      const bf16x8 pa = __builtin_bit_cast(bf16x8, wv);
#pragma unroll
      for (int ni = 0; ni < 4; ++ni) {
        const int row = ni * 16 + lr;
        bf16x8 vf = *(const bf16x8*)(Vp + SWZ(row, kk * 4 + lg));
        o[ni] = __builtin_amdgcn_mfma_f32_16x16x32_bf16(pa, vf, o[ni], 0, 0, 0);
      }
    }
  }
  const float lv0 = __shfl(lrow, abase + 0, 64);
  const float lv1 = __shfl(lrow, abase + 1, 64);
  const float lv2 = __shfl(lrow, abase + 2, 64);
  const float lv3 = __shfl(lrow, abase + 3, 64);
  const f32x4 lv = {lv0, lv1, lv2, lv3};
#pragma unroll
  for (int ni = 0; ni < 4; ++ni)
#pragma unroll
    for (int r = 0; r < 4; ++r) {
      const size_t orow = (size_t)(qb * 64 + w * 16 + lg * 4 + r);
      O[orow * DMODEL + h * HD + ni * 16 + lr] = f2bf(o[ni][r] / lv[r]);
    }
}

// ---------------- launcher ----------------
extern "C" void kernel_launch(void* const* d_in, const int* in_sizes, int n_in,
                              void* d_out, int out_size, void* d_ws, size_t ws_size,
                              hipStream_t stream) {
  const float* x   = (const float*)d_in[0];
  const float* wq  = (const float*)d_in[1];
  const float* wk  = (const float*)d_in[2];
  const float* wv  = (const float*)d_in[3];
  const float* wo  = (const float*)d_in[4];
  const float* qnw = (const float*)d_in[5];
  const float* knw = (const float*)d_in[6];
  const float* fc  = (const float*)d_in[7];
  const float* fs  = (const float*)d_in[8];
  float* out = (float*)d_out;

  char* ws = (char*)d_ws;
  size_t off = 0;
  auto alloc = [&](size_t bytes) {
    char* p = ws + off;
    off += (bytes + 255) & ~(size_t)255;
    return p;
  };
  const int NQKV = DMODEL + 512;  // 4608
  u16*   xb    = (u16*)alloc((size_t)S_LEN * DMODEL * 2);
  u16*   wqkvT = (u16*)alloc((size_t)NQKV * DMODEL * 2);
  float* P0    = (float*)alloc((size_t)S_LEN * NQKV * 4);
  float* P1    = (float*)alloc((size_t)S_LEN * NQKV * 4);
  u16*   Qn    = (u16*)alloc((size_t)S_LEN * DMODEL * 2);
  u16*   Kn    = (u16*)alloc((size_t)S_LEN * 256 * 2);
  u16*   VTb   = (u16*)alloc((size_t)256 * S_LEN * 2);
  u16*   Ob    = (u16*)alloc((size_t)S_LEN * DMODEL * 2);
  // overlays (regions dead by the time these are used):
  u16*   woT   = (u16*)P1;   // 32MB <= 37.75MB, used after norm_rope/V-extract
  float* Po1   = P0;         // out-proj split-K partial, used after attn

  hipFuncSetAttribute((const void*)gemm8, hipFuncAttributeMaxDynamicSharedMemorySize, 131072);

  cvt_f32_bf16_v4<<<(S_LEN * DMODEL / 4) / 256, 256, 0, stream>>>(x, xb);
  tconvs<<<(4096 / 32) * (4096 / 32), 256, 0, stream>>>(wq, nullptr, 4096, wqkvT, 4096, 4096);
  tconvs<<<(4096 / 32) * (256 / 32), 256, 0, stream>>>(wk, nullptr, 256,
      wqkvT + (size_t)4096 * 4096, 4096, 256);
  tconvs<<<(4096 / 32) * (256 / 32), 256, 0, stream>>>(wv, nullptr, 256,
      wqkvT + (size_t)4352 * 4096, 4096, 256);

  // fused QKV projection, split-K=2 partials P0/P1
  gemm8<<<2 * (2048 / 256) * (NQKV / 256), 512, 131072, stream>>>(
      xb, wqkvT, P0, P1, 2048, NQKV, 4096);

  const float QSCALE = 0.125f * 1.44269504088896340736f;
  norm_rope<<<(S_LEN * NH) / 4, 256, 0, stream>>>(P0, P1, NQKV, NH, qnw, fc, fs,
                                                  Qn, DMODEL, QSCALE);
  norm_rope<<<(S_LEN * NKV) / 4, 256, 0, stream>>>(P0 + 4096, P1 + 4096, NQKV, NKV,
                                                   knw, fc, fs, Kn, 256, 1.0f);
  // V^T: V partials (2048 x 256, row stride 4608) -> VT (256 x 2048 bf16)
  tconvs<<<(2048 / 32) * (256 / 32), 256, 0, stream>>>(P0 + 4352, P1 + 4352, NQKV,
                                                       VTb, 2048, 256);
  // wo transpose (overlays P1 -- P0/P1 dead from here on)
  tconvs<<<(4096 / 32) * (4096 / 32), 256, 0, stream>>>(wo, nullptr, 4096, woT, 4096, 4096);

  attn_fwd<<<(S_LEN / 64) * NH, 256, 0, stream>>>(Qn, Kn, VTb, Ob);

  // out projection, split-K=2: slice0 -> out, slice1 -> Po1, then add
  gemm8<<<2 * (2048 / 256) * (4096 / 256), 512, 131072, stream>>>(
      Ob, woT, out, Po1, 2048, 4096, 4096);
  addv4<<<(S_LEN * DMODEL / 4) / 256, 256, 0, stream>>>(out, Po1);
}

// Round 6
// 372.638 us; speedup vs baseline: 1.3043x; 1.0009x over previous
//
#include <hip/hip_runtime.h>
#include <hip/hip_bf16.h>

typedef unsigned short u16;
typedef unsigned int   u32;
typedef __attribute__((ext_vector_type(8))) __bf16 bf16x8;
typedef __attribute__((ext_vector_type(4))) float  f32x4;
typedef __attribute__((ext_vector_type(8))) u16    u16x8;
typedef __attribute__((ext_vector_type(4))) u16    u16x4;
typedef __attribute__((ext_vector_type(4))) u32    u32x4;

#define S_LEN 2048
#define DMODEL 4096
#define NH 64
#define NKV 4
#define HD 64

__device__ __forceinline__ u16 f2bf(float f) {
  u32 u = __builtin_bit_cast(u32, f);
  u32 r = (u + 0x7FFFu + ((u >> 16) & 1u)) >> 16;
  return (u16)r;
}
__device__ __forceinline__ u16 bfc(float f) {
  return __builtin_bit_cast(u16, (__bf16)f);
}
__device__ __forceinline__ u32 pk2(float lo, float hi) {
  return (u32)bfc(lo) | ((u32)bfc(hi) << 16);
}

__device__ __forceinline__ void gll16(const void* g, void* l) {
  __builtin_amdgcn_global_load_lds(
      (__attribute__((address_space(1))) void*)g,
      (__attribute__((address_space(3))) void*)l, 16, 0, 0);
}

// swizzled byte offset within a [rows][8 chunks of 16B] tile (128B row stride)
#define SWZ(row, chunk) (((row) * 128) + ((((chunk) ^ ((row) & 7))) << 4))

// ---------------- elementwise converts ----------------
__global__ __launch_bounds__(256) void cvt_f32_bf16_v4(const float* __restrict__ in,
                                                       u16* __restrict__ out) {
  const int i = blockIdx.x * 256 + threadIdx.x;
  float4 f = ((const float4*)in)[i];
  u16x4 u = { f2bf(f.x), f2bf(f.y), f2bf(f.z), f2bf(f.w) };
  *(u16x4*)&out[(size_t)i * 4] = u;
}

// out[i] += addend[i], float4
__global__ __launch_bounds__(256) void addv4(float* __restrict__ out,
                                             const float* __restrict__ addend) {
  const int i = blockIdx.x * 256 + threadIdx.x;
  float4 a = ((const float4*)addend)[i];
  float4 o = ((float4*)out)[i];
  o.x += a.x; o.y += a.y; o.z += a.z; o.w += a.w;
  ((float4*)out)[i] = o;
}

// transpose-convert (optionally summing two fp32 srcs): in R x C (row stride istride)
// -> out bf16 C x R
__global__ __launch_bounds__(256) void tconvs(const float* __restrict__ in,
                                              const float* __restrict__ in2, int istride,
                                              u16* __restrict__ out, int R, int C) {
  __shared__ float tile[32][33];
  const int nc = C >> 5;
  const int cb = blockIdx.x % nc, rb = blockIdx.x / nc;
  const int tx = threadIdx.x & 31, ty = threadIdx.x >> 5;
#pragma unroll
  for (int i = 0; i < 4; ++i) {
    const size_t idx = (size_t)(rb * 32 + ty + i * 8) * istride + cb * 32 + tx;
    float v = in[idx];
    if (in2) v += in2[idx];
    tile[ty + i * 8][tx] = v;
  }
  __syncthreads();
#pragma unroll
  for (int i = 0; i < 4; ++i)
    out[(size_t)(cb * 32 + ty + i * 8) * R + rb * 32 + tx] = f2bf(tile[tx][ty + i * 8]);
}

// ---------------- RMSNorm + RoPE (one wave = one (s,head) row of 64) ------------
// reads in[idx] + in2[idx] (split-K partials)
__global__ __launch_bounds__(256) void norm_rope(const float* __restrict__ in,
                                                 const float* __restrict__ in2,
                                                 int in_stride, int nheads,
                                                 const float* __restrict__ nw,
                                                 const float* __restrict__ cosT,
                                                 const float* __restrict__ sinT,
                                                 u16* __restrict__ outp, int out_stride,
                                                 float oscale) {
  const int wid = blockIdx.x * 4 + (threadIdx.x >> 6);
  const int l = threadIdx.x & 63;
  const int s = wid / nheads, h = wid - s * nheads;
  const size_t idx = (size_t)s * in_stride + h * 64 + l;
  const float v = in[idx] + in2[idx];
  float sq = v * v;
#pragma unroll
  for (int off = 32; off; off >>= 1) sq += __shfl_xor(sq, off, 64);
  const float rr = rsqrtf(sq * (1.f / 64.f) + 1e-5f);
  const float vn = v * rr * nw[l];
  const float p = __shfl_xor(vn, 1, 64);
  const int i2 = l >> 1;
  const float c = cosT[(size_t)s * 32 + i2];
  const float sn = sinT[(size_t)s * 32 + i2];
  const float o = ((l & 1) ? fmaf(p, sn, vn * c) : fmaf(-p, sn, vn * c)) * oscale;
  outp[(size_t)s * out_stride + h * 64 + l] = f2bf(o);
}

// ---------------- big GEMM: 256x256 tile, split-K=2, 8 waves (2Mx4N, 128x64/wave)
// LDS 128KB = 4 pages x 32KB; page = 32-k slice { A 16KB | B 16KB }.
// Depth-3 prefetch: stage(ph+3) in flight, steady-state vmcnt(8) (12 loads out,
// wait only for the phase being consumed). Each 128B LDS row packs two global
// rows' 32-k (64B) slices; 16B slots XOR-swizzled.
__global__ __launch_bounds__(512, 2) void gemm8(const u16* __restrict__ A,
                                                const u16* __restrict__ Bt,
                                                float* __restrict__ C0,
                                                float* __restrict__ C1,
                                                int M, int N, int K) {
  extern __shared__ __align__(16) char lds[];
  const int nbm = M >> 8, nbn = N >> 8;
  int bid = blockIdx.x;
  const int cpx = gridDim.x >> 3;
  bid = (bid & 7) * cpx + (bid >> 3);
  const int pertile = nbm * nbn;
  const int sl = bid / pertile;
  const int rem = bid - sl * pertile;
  const int bm = rem / nbn, bn = rem % nbn;
  const int m0 = bm << 8, n0 = bn << 8;
  const int t = threadIdx.x, w = t >> 6, l = t & 63;
  const int wr = w >> 2, wc = w & 3;            // waves 2(M) x 4(N); per-wave 128x64
  const int lr = l & 15, lg = l >> 4;

  const int Khalf = K >> 1;
  const int kbase = sl * Khalf;

  // staging: thread t -> LDS rows sR / sR+64 (A and B), slot t&7 (linear dest)
  const int sR = t >> 3, slot = t & 7;
  const int su = slot ^ (sR & 7);
  const int d1 = sR * 128 + slot * 16;
  const u16* Ag = A + (size_t)(m0 + 2 * sR + (su >> 2)) * K + kbase + (su & 3) * 8;
  const u16* Bg = Bt + (size_t)(n0 + 2 * sR + (su >> 2)) * K + kbase + (su & 3) * 8;
  const size_t r128 = (size_t)128 * K;

  f32x4 acc[8][4] = {};
  const int NPH = Khalf >> 5;

  auto stage = [&](int ph) {
    const int kofs = ph * 32;
    char* pb = lds + (ph & 3) * 32768;
    gll16(Ag + kofs, pb + d1);
    gll16(Ag + r128 + kofs, pb + 8192 + d1);
    gll16(Bg + kofs, pb + 16384 + d1);
    gll16(Bg + r128 + kofs, pb + 24576 + d1);
  };
  stage(0);
  stage(1);
  stage(2);

  const int sfrag = ((lr & 1) << 2) | lg;
  const int swz = (sfrag ^ ((lr >> 1) & 7)) << 4;
  const int aoff = (wr * 64 + (lr >> 1)) * 128 + swz;
  const int boff = 16384 + (wc * 32 + (lr >> 1)) * 128 + swz;

  auto compute = [&](int ph) {
    const char* base = lds + (ph & 3) * 32768;
    bf16x8 a[8], b[4];
#pragma unroll
    for (int mf = 0; mf < 8; ++mf) a[mf] = *(const bf16x8*)(base + aoff + mf * 1024);
#pragma unroll
    for (int nf = 0; nf < 4; ++nf) b[nf] = *(const bf16x8*)(base + boff + nf * 1024);
    __builtin_amdgcn_s_setprio(1);
#pragma unroll
    for (int mf = 0; mf < 8; ++mf)
#pragma unroll
      for (int nf = 0; nf < 4; ++nf)
        acc[mf][nf] = __builtin_amdgcn_mfma_f32_16x16x32_bf16(a[mf], b[nf], acc[mf][nf], 0, 0, 0);
    __builtin_amdgcn_s_setprio(0);
    asm volatile("" ::: "memory");
  };

#pragma unroll 4
  for (int ph = 0; ph < NPH - 3; ++ph) {
    __builtin_amdgcn_sched_barrier(0);
    asm volatile("s_waitcnt vmcnt(8)" ::: "memory");
    __builtin_amdgcn_s_barrier();
    stage(ph + 3);
    compute(ph);
  }
  __builtin_amdgcn_sched_barrier(0);
  asm volatile("s_waitcnt vmcnt(8)" ::: "memory");
  __builtin_amdgcn_s_barrier();
  compute(NPH - 3);
  __builtin_amdgcn_sched_barrier(0);
  asm volatile("s_waitcnt vmcnt(4)" ::: "memory");
  __builtin_amdgcn_s_barrier();
  compute(NPH - 2);
  __builtin_amdgcn_sched_barrier(0);
  asm volatile("s_waitcnt vmcnt(0)" ::: "memory");
  __builtin_amdgcn_s_barrier();
  compute(NPH - 1);

  float* Cs = sl ? C1 : C0;
#pragma unroll
  for (int mf = 0; mf < 8; ++mf)
#pragma unroll
    for (int nf = 0; nf < 4; ++nf)
#pragma unroll
      for (int rr = 0; rr < 4; ++rr)
        Cs[(size_t)(m0 + wr * 128 + mf * 16 + lg * 4 + rr) * N +
           (n0 + wc * 64 + nf * 16 + lr)] = acc[mf][nf][rr];
}

// ---------------- flash attention (causal, GQA), swapped-QK^T, in-register P ----
// Double-buffered K/V staging (raw barrier + vmcnt(0)), defer-rescale (THR=8 in
// exp2 domain). Q pre-scaled by 0.125*log2(e).
__global__ __launch_bounds__(256) void attn_fwd(const u16* __restrict__ Q,
                                                const u16* __restrict__ Kb,
                                                const u16* __restrict__ VT,
                                                u16* __restrict__ O) {
  const int h = blockIdx.x & 63;
  const int qb = (S_LEN / 64 - 1) - (blockIdx.x >> 6);  // big blocks first
  const int kvh = h >> 4;
  __shared__ __align__(16) char KV[2 * 16384];  // page: K 8KB | V 8KB
  const int tid = threadIdx.x;
  const int w = tid >> 6, l = tid & 63;
  const int lr = l & 15, lg = l >> 4;

  const int srow = w * 16 + (l >> 3);
  const int s0 = (l & 7) ^ (srow & 7);                          // inverse bank swizzle
  const int sv = (s0 & 4) | ((s0 & 1) << 1) | ((s0 & 2) >> 1);  // + pi for V packs
  const char* Kg = (const char*)Kb + kvh * 128 + (size_t)srow * 512 + s0 * 16;
  const char* Vg = (const char*)VT + (size_t)(kvh * 64 + srow) * (S_LEN * 2) + sv * 16;
  const int wofs = w * 2048;

  auto stage = [&](int page) {
    char* pb = KV + page * 16384 + wofs;
    gll16(Kg, pb);
    gll16(Kg + 8 * 512, pb + 1024);
    gll16(Vg, pb + 8192);
    gll16(Vg + 8 * (S_LEN * 2), pb + 8192 + 1024);
    Kg += 64 * 512;
    Vg += 128;
  };

  bf16x8 qf[2];
  {
    const size_t qoff = (size_t)(qb * 64 + w * 16 + lr) * DMODEL + h * HD + lg * 8;
    qf[0] = *(const bf16x8*)&Q[qoff];
    qf[1] = *(const bf16x8*)&Q[qoff + 32];
  }
  f32x4 o[4] = {};
  float mrow = -1e30f, lrow = 0.f;
  const int qlane = qb * 64 + w * 16 + lr;          // this lane's softmax q-row
  const int abase = (l & 48) | ((l >> 2) & 12);     // lane holding q = lg*4+r is abase+r

  stage(0);

  for (int t = 0; t <= qb; ++t) {
    __builtin_amdgcn_sched_barrier(0);
    asm volatile("s_waitcnt vmcnt(0)" ::: "memory");
    __builtin_amdgcn_s_barrier();
    __builtin_amdgcn_sched_barrier(0);
    if (t < qb) stage((t + 1) & 1);
    const char* Kp = KV + (t & 1) * 16384;
    const char* Vp = Kp + 8192;

    // S^T = K @ Q^T : lane holds S[q=lr][kv = t*64 + ni*16 + lg*4 + r]
    f32x4 sf[4] = {};
#pragma unroll
    for (int ni = 0; ni < 4; ++ni) {
      const int row = ni * 16 + lr;
      bf16x8 kf0 = *(const bf16x8*)(Kp + SWZ(row, lg));
      bf16x8 kf1 = *(const bf16x8*)(Kp + SWZ(row, 4 + lg));
      sf[ni] = __builtin_amdgcn_mfma_f32_16x16x32_bf16(kf0, qf[0], sf[ni], 0, 0, 0);
      sf[ni] = __builtin_amdgcn_mfma_f32_16x16x32_bf16(kf1, qf[1], sf[ni], 0, 0, 0);
    }
    if (t == qb) {
      const int kvb = t * 64 + lg * 4;
#pragma unroll
      for (int ni = 0; ni < 4; ++ni)
#pragma unroll
        for (int r = 0; r < 4; ++r)
          if (kvb + ni * 16 + r > qlane) sf[ni][r] = -1e30f;
    }
    float mt = -1e30f;
#pragma unroll
    for (int ni = 0; ni < 4; ++ni)
#pragma unroll
      for (int r = 0; r < 4; ++r) mt = fmaxf(mt, sf[ni][r]);
    mt = fmaxf(mt, __shfl_xor(mt, 16, 64));
    mt = fmaxf(mt, __shfl_xor(mt, 32, 64));

    if (__any(mt > mrow + 8.f)) {        // rescale only when the max really grows
      const float mn = fmaxf(mrow, mt);
      const float alpha = exp2f(mrow - mn);
      mrow = mn;
      lrow *= alpha;
      const float av0 = __shfl(alpha, abase + 0, 64);
      const float av1 = __shfl(alpha, abase + 1, 64);
      const float av2 = __shfl(alpha, abase + 2, 64);
      const float av3 = __shfl(alpha, abase + 3, 64);
#pragma unroll
      for (int ni = 0; ni < 4; ++ni) {
        o[ni][0] *= av0; o[ni][1] *= av1; o[ni][2] *= av2; o[ni][3] *= av3;
      }
    }
    float p[4][4];
    float rs = 0.f;
#pragma unroll
    for (int ni = 0; ni < 4; ++ni)
#pragma unroll
      for (int r = 0; r < 4; ++r) {
        const float e = exp2f(sf[ni][r] - mrow);
        p[ni][r] = e;
        rs += e;
      }
    rs += __shfl_xor(rs, 16, 64);
    rs += __shfl_xor(rs, 32, 64);
    lrow += rs;

    // O += P @ V : build A-fragments in-register (packs + xor16 exchange)
    const bool odd = (lg & 1);
#pragma unroll
    for (int kk = 0; kk < 2; ++kk) {
      const int nA = 2 * kk, nB = 2 * kk + 1;
      const u32 cA0 = pk2(p[nA][0], p[nA][1]), cA1 = pk2(p[nA][2], p[nA][3]);
      const u32 cB0 = pk2(p[nB][0], p[nB][1]), cB1 = pk2(p[nB][2], p[nB][3]);
      const u32 cS0 = odd ? cB0 : cA0, cS1 = odd ? cB1 : cA1;
      const u32 cP0 = odd ? cA0 : cB0, cP1 = odd ? cA1 : cB1;
      const u32 rP0 = (u32)__shfl_xor((int)cP0, 16, 64);
      const u32 rP1 = (u32)__shfl_xor((int)cP1, 16, 64);
      u32x4 wv;
      wv[0] = odd ? rP0 : cS0;
      wv[1] = odd ? rP1 : cS1;
      wv[2] = odd ? cS0 : rP0;
      wv[3] = odd ? cS1 : rP1;
      const bf16x8 pa = __builtin_bit_cast(bf16x8, wv);
#pragma unroll
      for (int ni = 0; ni < 4; ++ni) {
        const int row = ni * 16 + lr;
        bf16x8 vf = *(const bf16x8*)(Vp + SWZ(row, kk * 4 + lg));
        o[ni] = __builtin_amdgcn_mfma_f32_16x16x32_bf16(pa, vf, o[ni], 0, 0, 0);
      }
    }
  }
  const float lv0 = __shfl(lrow, abase + 0, 64);
  const float lv1 = __shfl(lrow, abase + 1, 64);
  const float lv2 = __shfl(lrow, abase + 2, 64);
  const float lv3 = __shfl(lrow, abase + 3, 64);
  const f32x4 lv = {lv0, lv1, lv2, lv3};
#pragma unroll
  for (int ni = 0; ni < 4; ++ni)
#pragma unroll
    for (int r = 0; r < 4; ++r) {
      const size_t orow = (size_t)(qb * 64 + w * 16 + lg * 4 + r);
      O[orow * DMODEL + h * HD + ni * 16 + lr] = f2bf(o[ni][r] / lv[r]);
    }
}

// ---------------- launcher ----------------
extern "C" void kernel_launch(void* const* d_in, const int* in_sizes, int n_in,
                              void* d_out, int out_size, void* d_ws, size_t ws_size,
                              hipStream_t stream) {
  const float* x   = (const float*)d_in[0];
  const float* wq  = (const float*)d_in[1];
  const float* wk  = (const float*)d_in[2];
  const float* wv  = (const float*)d_in[3];
  const float* wo  = (const float*)d_in[4];
  const float* qnw = (const float*)d_in[5];
  const float* knw = (const float*)d_in[6];
  const float* fc  = (const float*)d_in[7];
  const float* fs  = (const float*)d_in[8];
  float* out = (float*)d_out;

  char* ws = (char*)d_ws;
  size_t off = 0;
  auto alloc = [&](size_t bytes) {
    char* p = ws + off;
    off += (bytes + 255) & ~(size_t)255;
    return p;
  };
  const int NQKV = DMODEL + 512;  // 4608
  u16*   xb    = (u16*)alloc((size_t)S_LEN * DMODEL * 2);
  u16*   wqkvT = (u16*)alloc((size_t)NQKV * DMODEL * 2);
  float* P0    = (float*)alloc((size_t)S_LEN * NQKV * 4);
  float* P1    = (float*)alloc((size_t)S_LEN * NQKV * 4);
  u16*   Qn    = (u16*)alloc((size_t)S_LEN * DMODEL * 2);
  u16*   Kn    = (u16*)alloc((size_t)S_LEN * 256 * 2);
  u16*   VTb   = (u16*)alloc((size_t)256 * S_LEN * 2);
  u16*   Ob    = (u16*)alloc((size_t)S_LEN * DMODEL * 2);
  // overlays (regions dead by the time these are used):
  u16*   woT   = (u16*)P1;   // 32MB <= 37.75MB, used after norm_rope/V-extract
  float* Po1   = P0;         // out-proj split-K partial, used after attn

  hipFuncSetAttribute((const void*)gemm8, hipFuncAttributeMaxDynamicSharedMemorySize, 131072);

  cvt_f32_bf16_v4<<<(S_LEN * DMODEL / 4) / 256, 256, 0, stream>>>(x, xb);
  tconvs<<<(4096 / 32) * (4096 / 32), 256, 0, stream>>>(wq, nullptr, 4096, wqkvT, 4096, 4096);
  tconvs<<<(4096 / 32) * (256 / 32), 256, 0, stream>>>(wk, nullptr, 256,
      wqkvT + (size_t)4096 * 4096, 4096, 256);
  tconvs<<<(4096 / 32) * (256 / 32), 256, 0, stream>>>(wv, nullptr, 256,
      wqkvT + (size_t)4352 * 4096, 4096, 256);

  // fused QKV projection, split-K=2 partials P0/P1
  gemm8<<<2 * (2048 / 256) * (NQKV / 256), 512, 131072, stream>>>(
      xb, wqkvT, P0, P1, 2048, NQKV, 4096);

  const float QSCALE = 0.125f * 1.44269504088896340736f;
  norm_rope<<<(S_LEN * NH) / 4, 256, 0, stream>>>(P0, P1, NQKV, NH, qnw, fc, fs,
                                                  Qn, DMODEL, QSCALE);
  norm_rope<<<(S_LEN * NKV) / 4, 256, 0, stream>>>(P0 + 4096, P1 + 4096, NQKV, NKV,
                                                   knw, fc, fs, Kn, 256, 1.0f);
  // V^T: V partials (2048 x 256, row stride 4608) -> VT (256 x 2048 bf16)
  tconvs<<<(2048 / 32) * (256 / 32), 256, 0, stream>>>(P0 + 4352, P1 + 4352, NQKV,
                                                       VTb, 2048, 256);
  // wo transpose (overlays P1 -- P0/P1 dead from here on)
  tconvs<<<(4096 / 32) * (4096 / 32), 256, 0, stream>>>(wo, nullptr, 4096, woT, 4096, 4096);

  attn_fwd<<<(S_LEN / 64) * NH, 256, 0, stream>>>(Qn, Kn, VTb, Ob);

  // out projection, split-K=2: slice0 -> out, slice1 -> Po1, then add
  gemm8<<<2 * (2048 / 256) * (4096 / 256), 512, 131072, stream>>>(
      Ob, woT, out, Po1, 2048, 4096, 4096);
  addv4<<<(S_LEN * DMODEL / 4) / 256, 256, 0, stream>>>(out, Po1);
}

// Round 7
// 362.704 us; speedup vs baseline: 1.3401x; 1.0274x over previous
//
#include <hip/hip_runtime.h>
#include <hip/hip_bf16.h>

typedef unsigned short u16;
typedef unsigned int   u32;
typedef __attribute__((ext_vector_type(8))) __bf16 bf16x8;
typedef __attribute__((ext_vector_type(4))) float  f32x4;
typedef __attribute__((ext_vector_type(8))) u16    u16x8;
typedef __attribute__((ext_vector_type(4))) u16    u16x4;
typedef __attribute__((ext_vector_type(4))) u32    u32x4;

#define S_LEN 2048
#define DMODEL 4096
#define NH 64
#define NKV 4
#define HD 64

__device__ __forceinline__ u16 f2bf(float f) {
  u32 u = __builtin_bit_cast(u32, f);
  u32 r = (u + 0x7FFFu + ((u >> 16) & 1u)) >> 16;
  return (u16)r;
}
__device__ __forceinline__ u16 bfc(float f) {
  return __builtin_bit_cast(u16, (__bf16)f);
}
__device__ __forceinline__ u32 pk2(float lo, float hi) {
  return (u32)bfc(lo) | ((u32)bfc(hi) << 16);
}
__device__ __forceinline__ float ex2(float x) { return __builtin_amdgcn_exp2f(x); }

__device__ __forceinline__ void gll16(const void* g, void* l) {
  __builtin_amdgcn_global_load_lds(
      (__attribute__((address_space(1))) void*)g,
      (__attribute__((address_space(3))) void*)l, 16, 0, 0);
}

// swizzled byte offset within a [rows][8 chunks of 16B] tile (128B row stride)
#define SWZ(row, chunk) (((row) * 128) + ((((chunk) ^ ((row) & 7))) << 4))

// ---------------- elementwise converts ----------------
__global__ __launch_bounds__(256) void cvt_f32_bf16_v4(const float* __restrict__ in,
                                                       u16* __restrict__ out) {
  const int i = blockIdx.x * 256 + threadIdx.x;
  float4 f = ((const float4*)in)[i];
  u16x4 u = { f2bf(f.x), f2bf(f.y), f2bf(f.z), f2bf(f.w) };
  *(u16x4*)&out[(size_t)i * 4] = u;
}

// out[i] += addend[i], float4
__global__ __launch_bounds__(256) void addv4(float* __restrict__ out,
                                             const float* __restrict__ addend) {
  const int i = blockIdx.x * 256 + threadIdx.x;
  float4 a = ((const float4*)addend)[i];
  float4 o = ((float4*)out)[i];
  o.x += a.x; o.y += a.y; o.z += a.z; o.w += a.w;
  ((float4*)out)[i] = o;
}

// transpose-convert (optionally summing two fp32 srcs): in R x C (row stride istride)
// -> out bf16 C x R
__global__ __launch_bounds__(256) void tconvs(const float* __restrict__ in,
                                              const float* __restrict__ in2, int istride,
                                              u16* __restrict__ out, int R, int C) {
  __shared__ float tile[32][33];
  const int nc = C >> 5;
  const int cb = blockIdx.x % nc, rb = blockIdx.x / nc;
  const int tx = threadIdx.x & 31, ty = threadIdx.x >> 5;
#pragma unroll
  for (int i = 0; i < 4; ++i) {
    const size_t idx = (size_t)(rb * 32 + ty + i * 8) * istride + cb * 32 + tx;
    float v = in[idx];
    if (in2) v += in2[idx];
    tile[ty + i * 8][tx] = v;
  }
  __syncthreads();
#pragma unroll
  for (int i = 0; i < 4; ++i)
    out[(size_t)(cb * 32 + ty + i * 8) * R + rb * 32 + tx] = f2bf(tile[tx][ty + i * 8]);
}

// ---------------- RMSNorm + RoPE (one wave = one (s,head) row of 64) ------------
// reads in[idx] + in2[idx] (split-K partials)
__global__ __launch_bounds__(256) void norm_rope(const float* __restrict__ in,
                                                 const float* __restrict__ in2,
                                                 int in_stride, int nheads,
                                                 const float* __restrict__ nw,
                                                 const float* __restrict__ cosT,
                                                 const float* __restrict__ sinT,
                                                 u16* __restrict__ outp, int out_stride,
                                                 float oscale) {
  const int wid = blockIdx.x * 4 + (threadIdx.x >> 6);
  const int l = threadIdx.x & 63;
  const int s = wid / nheads, h = wid - s * nheads;
  const size_t idx = (size_t)s * in_stride + h * 64 + l;
  const float v = in[idx] + in2[idx];
  float sq = v * v;
#pragma unroll
  for (int off = 32; off; off >>= 1) sq += __shfl_xor(sq, off, 64);
  const float rr = rsqrtf(sq * (1.f / 64.f) + 1e-5f);
  const float vn = v * rr * nw[l];
  const float p = __shfl_xor(vn, 1, 64);
  const int i2 = l >> 1;
  const float c = cosT[(size_t)s * 32 + i2];
  const float sn = sinT[(size_t)s * 32 + i2];
  const float o = ((l & 1) ? fmaf(p, sn, vn * c) : fmaf(-p, sn, vn * c)) * oscale;
  outp[(size_t)s * out_stride + h * 64 + l] = f2bf(o);
}

// ---------------- KV projection: 128x128 tiles, split-K=2 ----------------
__global__ __launch_bounds__(256) void gemm_kv(const u16* __restrict__ A,
                                               const u16* __restrict__ Bt,
                                               float* __restrict__ C0,
                                               float* __restrict__ C1,
                                               int M, int N, int K) {
  __shared__ __align__(16) u16 As[128 * 32];
  __shared__ __align__(16) u16 Bs[128 * 32];
  int bid = blockIdx.x;
  const int cpx = gridDim.x >> 3;
  bid = (bid & 7) * cpx + (bid >> 3);
  const int nbn = N >> 7;
  const int pertile = (M >> 7) * nbn;
  const int sl = bid / pertile;
  const int rem = bid - sl * pertile;
  const int bm = rem / nbn, bn = rem % nbn;
  const int m0 = bm << 7, n0 = bn << 7;
  const int tid = threadIdx.x;
  const int w = tid >> 6, l = tid & 63;
  const int wr = w >> 1, wc = w & 1;
  f32x4 acc[4][4] = {};

  const int Khalf = K >> 1;
  const int kbase = sl * Khalf;

  const char* Ag = (const char*)A +
      ((size_t)(m0 + w * 32 + (l >> 2)) * K + kbase + (l & 3) * 8) * 2;
  const char* Bg = (const char*)Bt +
      ((size_t)(n0 + w * 32 + (l >> 2)) * K + kbase + (l & 3) * 8) * 2;
  char* Al = (char*)As + (w * 32) * 64;
  char* Bl = (char*)Bs + (w * 32) * 64;
  const size_t rowadv = (size_t)16 * K * 2;

  for (int k0 = 0; k0 < Khalf; k0 += 32) {
    gll16(Ag, Al);
    gll16(Ag + rowadv, Al + 1024);
    gll16(Bg, Bl);
    gll16(Bg + rowadv, Bl + 1024);
    Ag += 64; Bg += 64;
    __syncthreads();
    bf16x8 af[4], bq[4];
#pragma unroll
    for (int i = 0; i < 4; ++i) {
      af[i] = *(const bf16x8*)&As[(wr * 64 + i * 16 + (l & 15)) * 32 + (l >> 4) * 8];
      bq[i] = *(const bf16x8*)&Bs[(wc * 64 + i * 16 + (l & 15)) * 32 + (l >> 4) * 8];
    }
#pragma unroll
    for (int mi = 0; mi < 4; ++mi)
#pragma unroll
      for (int ni = 0; ni < 4; ++ni)
        acc[mi][ni] = __builtin_amdgcn_mfma_f32_16x16x32_bf16(af[mi], bq[ni], acc[mi][ni], 0, 0, 0);
    __syncthreads();
  }
  float* Cs = sl ? C1 : C0;
  const int r0 = (l >> 4) * 4, c0 = l & 15;
#pragma unroll
  for (int mi = 0; mi < 4; ++mi)
#pragma unroll
    for (int ni = 0; ni < 4; ++ni)
#pragma unroll
      for (int r = 0; r < 4; ++r)
        Cs[(size_t)(m0 + wr * 64 + mi * 16 + r0 + r) * N + (n0 + wc * 64 + ni * 16 + c0)] =
            acc[mi][ni][r];
}

// ---------------- big GEMM: 256x256 tile, split-K=2, 8 waves (2Mx4N, 128x64/wave)
// LDS 128KB = 4 pages x 32KB; page = 32-k slice { A 16KB | B 16KB }.
// Depth-3 prefetch, steady-state vmcnt(8). 128B LDS rows pack two global rows'
// 32-k (64B) slices; 16B slots XOR-swizzled.
__global__ __launch_bounds__(512, 2) void gemm8(const u16* __restrict__ A,
                                                const u16* __restrict__ Bt,
                                                float* __restrict__ C0,
                                                float* __restrict__ C1,
                                                int M, int N, int K) {
  extern __shared__ __align__(16) char lds[];
  const int nbm = M >> 8, nbn = N >> 8;
  int bid = blockIdx.x;
  const int cpx = gridDim.x >> 3;
  bid = (bid & 7) * cpx + (bid >> 3);
  const int pertile = nbm * nbn;
  const int sl = bid / pertile;
  const int rem = bid - sl * pertile;
  const int bm = rem / nbn, bn = rem % nbn;
  const int m0 = bm << 8, n0 = bn << 8;
  const int t = threadIdx.x, w = t >> 6, l = t & 63;
  const int wr = w >> 2, wc = w & 3;            // waves 2(M) x 4(N); per-wave 128x64
  const int lr = l & 15, lg = l >> 4;

  const int Khalf = K >> 1;
  const int kbase = sl * Khalf;

  const int sR = t >> 3, slot = t & 7;
  const int su = slot ^ (sR & 7);
  const int d1 = sR * 128 + slot * 16;
  const u16* Ag = A + (size_t)(m0 + 2 * sR + (su >> 2)) * K + kbase + (su & 3) * 8;
  const u16* Bg = Bt + (size_t)(n0 + 2 * sR + (su >> 2)) * K + kbase + (su & 3) * 8;
  const size_t r128 = (size_t)128 * K;

  f32x4 acc[8][4] = {};
  const int NPH = Khalf >> 5;

  auto stage = [&](int ph) {
    const int kofs = ph * 32;
    char* pb = lds + (ph & 3) * 32768;
    gll16(Ag + kofs, pb + d1);
    gll16(Ag + r128 + kofs, pb + 8192 + d1);
    gll16(Bg + kofs, pb + 16384 + d1);
    gll16(Bg + r128 + kofs, pb + 24576 + d1);
  };
  stage(0);
  stage(1);
  stage(2);

  const int sfrag = ((lr & 1) << 2) | lg;
  const int swz = (sfrag ^ ((lr >> 1) & 7)) << 4;
  const int aoff = (wr * 64 + (lr >> 1)) * 128 + swz;
  const int boff = 16384 + (wc * 32 + (lr >> 1)) * 128 + swz;

  auto compute = [&](int ph) {
    const char* base = lds + (ph & 3) * 32768;
    bf16x8 a[8], b[4];
#pragma unroll
    for (int mf = 0; mf < 8; ++mf) a[mf] = *(const bf16x8*)(base + aoff + mf * 1024);
#pragma unroll
    for (int nf = 0; nf < 4; ++nf) b[nf] = *(const bf16x8*)(base + boff + nf * 1024);
    __builtin_amdgcn_s_setprio(1);
#pragma unroll
    for (int mf = 0; mf < 8; ++mf)
#pragma unroll
      for (int nf = 0; nf < 4; ++nf)
        acc[mf][nf] = __builtin_amdgcn_mfma_f32_16x16x32_bf16(a[mf], b[nf], acc[mf][nf], 0, 0, 0);
    __builtin_amdgcn_s_setprio(0);
    asm volatile("" ::: "memory");
  };

#pragma unroll 4
  for (int ph = 0; ph < NPH - 3; ++ph) {
    __builtin_amdgcn_sched_barrier(0);
    asm volatile("s_waitcnt vmcnt(8)" ::: "memory");
    __builtin_amdgcn_s_barrier();
    stage(ph + 3);
    compute(ph);
  }
  __builtin_amdgcn_sched_barrier(0);
  asm volatile("s_waitcnt vmcnt(8)" ::: "memory");
  __builtin_amdgcn_s_barrier();
  compute(NPH - 3);
  __builtin_amdgcn_sched_barrier(0);
  asm volatile("s_waitcnt vmcnt(4)" ::: "memory");
  __builtin_amdgcn_s_barrier();
  compute(NPH - 2);
  __builtin_amdgcn_sched_barrier(0);
  asm volatile("s_waitcnt vmcnt(0)" ::: "memory");
  __builtin_amdgcn_s_barrier();
  compute(NPH - 1);

  float* Cs = sl ? C1 : C0;
#pragma unroll
  for (int mf = 0; mf < 8; ++mf)
#pragma unroll
    for (int nf = 0; nf < 4; ++nf)
#pragma unroll
      for (int rr = 0; rr < 4; ++rr)
        Cs[(size_t)(m0 + wr * 128 + mf * 16 + lg * 4 + rr) * N +
           (n0 + wc * 64 + nf * 16 + lr)] = acc[mf][nf][rr];
}

// ---------------- flash attention (causal, GQA), swapped-QK^T, in-register P ----
// Double-buffered K/V staging (raw barrier + vmcnt(0)), defer-rescale (THR=8 in
// exp2 domain). Q pre-scaled by 0.125*log2(e).
__global__ __launch_bounds__(256) void attn_fwd(const u16* __restrict__ Q,
                                                const u16* __restrict__ Kb,
                                                const u16* __restrict__ VT,
                                                u16* __restrict__ O) {
  const int h = blockIdx.x & 63;
  const int qb = (S_LEN / 64 - 1) - (blockIdx.x >> 6);  // big blocks first
  const int kvh = h >> 4;
  __shared__ __align__(16) char KV[2 * 16384];  // page: K 8KB | V 8KB
  const int tid = threadIdx.x;
  const int w = tid >> 6, l = tid & 63;
  const int lr = l & 15, lg = l >> 4;

  const int srow = w * 16 + (l >> 3);
  const int s0 = (l & 7) ^ (srow & 7);                          // inverse bank swizzle
  const int sv = (s0 & 4) | ((s0 & 1) << 1) | ((s0 & 2) >> 1);  // + pi for V packs
  const char* Kg = (const char*)Kb + kvh * 128 + (size_t)srow * 512 + s0 * 16;
  const char* Vg = (const char*)VT + (size_t)(kvh * 64 + srow) * (S_LEN * 2) + sv * 16;
  const int wofs = w * 2048;

  auto stage = [&](int page) {
    char* pb = KV + page * 16384 + wofs;
    gll16(Kg, pb);
    gll16(Kg + 8 * 512, pb + 1024);
    gll16(Vg, pb + 8192);
    gll16(Vg + 8 * (S_LEN * 2), pb + 8192 + 1024);
    Kg += 64 * 512;
    Vg += 128;
  };

  bf16x8 qf[2];
  {
    const size_t qoff = (size_t)(qb * 64 + w * 16 + lr) * DMODEL + h * HD + lg * 8;
    qf[0] = *(const bf16x8*)&Q[qoff];
    qf[1] = *(const bf16x8*)&Q[qoff + 32];
  }
  f32x4 o[4] = {};
  float mrow = -1e30f, lrow = 0.f;
  const int qlane = qb * 64 + w * 16 + lr;          // this lane's softmax q-row
  const int abase = (l & 48) | ((l >> 2) & 12);     // lane holding q = lg*4+r is abase+r

  stage(0);

  for (int t = 0; t <= qb; ++t) {
    __builtin_amdgcn_sched_barrier(0);
    asm volatile("s_waitcnt vmcnt(0)" ::: "memory");
    __builtin_amdgcn_s_barrier();
    __builtin_amdgcn_sched_barrier(0);
    if (t < qb) stage((t + 1) & 1);
    const char* Kp = KV + (t & 1) * 16384;
    const char* Vp = Kp + 8192;

    // S^T = K @ Q^T : lane holds S[q=lr][kv = t*64 + ni*16 + lg*4 + r]
    f32x4 sf[4] = {};
#pragma unroll
    for (int ni = 0; ni < 4; ++ni) {
      const int row = ni * 16 + lr;
      bf16x8 kf0 = *(const bf16x8*)(Kp + SWZ(row, lg));
      bf16x8 kf1 = *(const bf16x8*)(Kp + SWZ(row, 4 + lg));
      sf[ni] = __builtin_amdgcn_mfma_f32_16x16x32_bf16(kf0, qf[0], sf[ni], 0, 0, 0);
      sf[ni] = __builtin_amdgcn_mfma_f32_16x16x32_bf16(kf1, qf[1], sf[ni], 0, 0, 0);
    }
    if (t == qb) {
      const int kvb = t * 64 + lg * 4;
#pragma unroll
      for (int ni = 0; ni < 4; ++ni)
#pragma unroll
        for (int r = 0; r < 4; ++r)
          if (kvb + ni * 16 + r > qlane) sf[ni][r] = -1e30f;
    }
    // tree max
    float m4[4];
#pragma unroll
    for (int ni = 0; ni < 4; ++ni)
      m4[ni] = fmaxf(fmaxf(sf[ni][0], sf[ni][1]), fmaxf(sf[ni][2], sf[ni][3]));
    float mt = fmaxf(fmaxf(m4[0], m4[1]), fmaxf(m4[2], m4[3]));
    mt = fmaxf(mt, __shfl_xor(mt, 16, 64));
    mt = fmaxf(mt, __shfl_xor(mt, 32, 64));

    if (__any(mt > mrow + 8.f)) {        // rescale only when the max really grows
      const float mn = fmaxf(mrow, mt);
      const float alpha = ex2(mrow - mn);
      mrow = mn;
      lrow *= alpha;
      const float av0 = __shfl(alpha, abase + 0, 64);
      const float av1 = __shfl(alpha, abase + 1, 64);
      const float av2 = __shfl(alpha, abase + 2, 64);
      const float av3 = __shfl(alpha, abase + 3, 64);
#pragma unroll
      for (int ni = 0; ni < 4; ++ni) {
        o[ni][0] *= av0; o[ni][1] *= av1; o[ni][2] *= av2; o[ni][3] *= av3;
      }
    }
    float p[4][4];
    float r4[4];
#pragma unroll
    for (int ni = 0; ni < 4; ++ni) {
#pragma unroll
      for (int r = 0; r < 4; ++r) p[ni][r] = ex2(sf[ni][r] - mrow);
      r4[ni] = (p[ni][0] + p[ni][1]) + (p[ni][2] + p[ni][3]);
    }
    float rs = (r4[0] + r4[1]) + (r4[2] + r4[3]);
    rs += __shfl_xor(rs, 16, 64);
    rs += __shfl_xor(rs, 32, 64);
    lrow += rs;

    // O += P @ V : build A-fragments in-register (packs + xor16 exchange)
    const bool odd = (lg & 1);
#pragma unroll
    for (int kk = 0; kk < 2; ++kk) {
      const int nA = 2 * kk, nB = 2 * kk + 1;
      const u32 cA0 = pk2(p[nA][0], p[nA][1]), cA1 = pk2(p[nA][2], p[nA][3]);
      const u32 cB0 = pk2(p[nB][0], p[nB][1]), cB1 = pk2(p[nB][2], p[nB][3]);
      const u32 cS0 = odd ? cB0 : cA0, cS1 = odd ? cB1 : cA1;
      const u32 cP0 = odd ? cA0 : cB0, cP1 = odd ? cA1 : cB1;
      const u32 rP0 = (u32)__shfl_xor((int)cP0, 16, 64);
      const u32 rP1 = (u32)__shfl_xor((int)cP1, 16, 64);
      u32x4 wv;
      wv[0] = odd ? rP0 : cS0;
      wv[1] = odd ? rP1 : cS1;
      wv[2] = odd ? cS0 : rP0;
      wv[3] = odd ? cS1 : rP1;
      const bf16x8 pa = __builtin_bit_cast(bf16x8, wv);
#pragma unroll
      for (int ni = 0; ni < 4; ++ni) {
        const int row = ni * 16 + lr;
        bf16x8 vf = *(const bf16x8*)(Vp + SWZ(row, kk * 4 + lg));
        o[ni] = __builtin_amdgcn_mfma_f32_16x16x32_bf16(pa, vf, o[ni], 0, 0, 0);
      }
    }
  }
  const float lv0 = __shfl(lrow, abase + 0, 64);
  const float lv1 = __shfl(lrow, abase + 1, 64);
  const float lv2 = __shfl(lrow, abase + 2, 64);
  const float lv3 = __shfl(lrow, abase + 3, 64);
  const f32x4 lv = {lv0, lv1, lv2, lv3};
#pragma unroll
  for (int ni = 0; ni < 4; ++ni)
#pragma unroll
    for (int r = 0; r < 4; ++r) {
      const size_t orow = (size_t)(qb * 64 + w * 16 + lg * 4 + r);
      O[orow * DMODEL + h * HD + ni * 16 + lr] = f2bf(o[ni][r] / lv[r]);
    }
}

// ---------------- launcher ----------------
extern "C" void kernel_launch(void* const* d_in, const int* in_sizes, int n_in,
                              void* d_out, int out_size, void* d_ws, size_t ws_size,
                              hipStream_t stream) {
  const float* x   = (const float*)d_in[0];
  const float* wq  = (const float*)d_in[1];
  const float* wk  = (const float*)d_in[2];
  const float* wv  = (const float*)d_in[3];
  const float* wo  = (const float*)d_in[4];
  const float* qnw = (const float*)d_in[5];
  const float* knw = (const float*)d_in[6];
  const float* fc  = (const float*)d_in[7];
  const float* fs  = (const float*)d_in[8];
  float* out = (float*)d_out;

  char* ws = (char*)d_ws;
  size_t off = 0;
  auto alloc = [&](size_t bytes) {
    char* p = ws + off;
    off += (bytes + 255) & ~(size_t)255;
    return p;
  };
  u16*   xb    = (u16*)alloc((size_t)S_LEN * DMODEL * 2);
  u16*   wqT   = (u16*)alloc((size_t)DMODEL * DMODEL * 2);
  u16*   wkvT  = (u16*)alloc((size_t)512 * DMODEL * 2);
  float* P0q   = (float*)alloc((size_t)S_LEN * DMODEL * 4);
  float* P1q   = (float*)alloc((size_t)S_LEN * DMODEL * 4);
  float* KV0   = (float*)alloc((size_t)S_LEN * 512 * 4);
  float* KV1   = (float*)alloc((size_t)S_LEN * 512 * 4);
  u16*   Qn    = (u16*)alloc((size_t)S_LEN * DMODEL * 2);
  u16*   Kn    = (u16*)alloc((size_t)S_LEN * 256 * 2);
  u16*   VTb   = (u16*)alloc((size_t)256 * S_LEN * 2);
  u16*   Ob    = (u16*)alloc((size_t)S_LEN * DMODEL * 2);
  // overlays (regions dead by the time these are used):
  u16*   woT   = (u16*)P1q;  // 32MB <= 33.5MB, used after norm_rope Q
  float* Po1   = P0q;        // out-proj split-K partial, used after attn

  hipFuncSetAttribute((const void*)gemm8, hipFuncAttributeMaxDynamicSharedMemorySize, 131072);

  cvt_f32_bf16_v4<<<(S_LEN * DMODEL / 4) / 256, 256, 0, stream>>>(x, xb);
  tconvs<<<(4096 / 32) * (4096 / 32), 256, 0, stream>>>(wq, nullptr, 4096, wqT, 4096, 4096);
  tconvs<<<(4096 / 32) * (256 / 32), 256, 0, stream>>>(wk, nullptr, 256, wkvT, 4096, 256);
  tconvs<<<(4096 / 32) * (256 / 32), 256, 0, stream>>>(wv, nullptr, 256,
      wkvT + (size_t)256 * 4096, 4096, 256);

  // Q projection: 8x16 tiles x split-K2 = 256 blocks (exactly one round)
  gemm8<<<2 * (2048 / 256) * (4096 / 256), 512, 131072, stream>>>(
      xb, wqT, P0q, P1q, 2048, 4096, 4096);
  // KV projection: 16x4 tiles x split-K2 = 128 blocks
  gemm_kv<<<2 * (2048 / 128) * (512 / 128), 256, 0, stream>>>(
      xb, wkvT, KV0, KV1, 2048, 512, 4096);

  const float QSCALE = 0.125f * 1.44269504088896340736f;
  norm_rope<<<(S_LEN * NH) / 4, 256, 0, stream>>>(P0q, P1q, DMODEL, NH, qnw, fc, fs,
                                                  Qn, DMODEL, QSCALE);
  norm_rope<<<(S_LEN * NKV) / 4, 256, 0, stream>>>(KV0, KV1, 512, NKV,
                                                   knw, fc, fs, Kn, 256, 1.0f);
  // V^T: V partials (2048 x 256, row stride 512) -> VT (256 x 2048 bf16)
  tconvs<<<(2048 / 32) * (256 / 32), 256, 0, stream>>>(KV0 + 256, KV1 + 256, 512,
                                                       VTb, 2048, 256);
  // wo transpose (overlays P1q -- P0q/P1q dead from here on)
  tconvs<<<(4096 / 32) * (4096 / 32), 256, 0, stream>>>(wo, nullptr, 4096, woT, 4096, 4096);

  attn_fwd<<<(S_LEN / 64) * NH, 256, 0, stream>>>(Qn, Kn, VTb, Ob);

  // out projection, split-K=2: slice0 -> out, slice1 -> Po1, then add
  gemm8<<<2 * (2048 / 256) * (4096 / 256), 512, 131072, stream>>>(
      Ob, woT, out, Po1, 2048, 4096, 4096);
  addv4<<<(S_LEN * DMODEL / 4) / 256, 256, 0, stream>>>(out, Po1);
}

// Round 8
// 332.680 us; speedup vs baseline: 1.4610x; 1.0902x over previous
//
#include <hip/hip_runtime.h>
#include <hip/hip_bf16.h>

typedef unsigned short u16;
typedef unsigned int   u32;
typedef __attribute__((ext_vector_type(8))) __bf16 bf16x8;
typedef __attribute__((ext_vector_type(4))) float  f32x4;
typedef __attribute__((ext_vector_type(8))) u16    u16x8;
typedef __attribute__((ext_vector_type(4))) u16    u16x4;
typedef __attribute__((ext_vector_type(2))) u32    u32x2;
typedef __attribute__((ext_vector_type(4))) u32    u32x4;

#define S_LEN 2048
#define DMODEL 4096
#define NH 64
#define NKV 4
#define HD 64

__device__ __forceinline__ u16 f2bf(float f) {
  u32 u = __builtin_bit_cast(u32, f);
  u32 r = (u + 0x7FFFu + ((u >> 16) & 1u)) >> 16;
  return (u16)r;
}
__device__ __forceinline__ u16 bfc(float f) {
  return __builtin_bit_cast(u16, (__bf16)f);
}
__device__ __forceinline__ u32 pk2(float lo, float hi) {
  return (u32)bfc(lo) | ((u32)bfc(hi) << 16);
}
__device__ __forceinline__ float bf2f(u16 u) {
  return __builtin_bit_cast(float, (u32)u << 16);
}
__device__ __forceinline__ float ex2(float x) { return __builtin_amdgcn_exp2f(x); }

__device__ __forceinline__ void gll16(const void* g, void* l) {
  __builtin_amdgcn_global_load_lds(
      (__attribute__((address_space(1))) void*)g,
      (__attribute__((address_space(3))) void*)l, 16, 0, 0);
}

// ---------------- elementwise converts ----------------
__global__ __launch_bounds__(256) void cvt_f32_bf16_v4(const float* __restrict__ in,
                                                       u16* __restrict__ out) {
  const int i = blockIdx.x * 256 + threadIdx.x;
  float4 f = ((const float4*)in)[i];
  u16x4 u = { f2bf(f.x), f2bf(f.y), f2bf(f.z), f2bf(f.w) };
  *(u16x4*)&out[(size_t)i * 4] = u;
}

// transpose-convert (optionally summing two fp32 srcs): in R x C (row stride istride)
// -> out bf16 C x R. Vectorized: float4 loads, 8B stores.
__global__ __launch_bounds__(256) void tconvs(const float* __restrict__ in,
                                              const float* __restrict__ in2, int istride,
                                              u16* __restrict__ out, int R, int C) {
  __shared__ __align__(16) float tile[32][36];
  const int nc = C >> 5;
  const int cb = blockIdx.x % nc, rb = blockIdx.x / nc;
  const int r = threadIdx.x >> 3, c4 = (threadIdx.x & 7) << 2;
  const size_t idx = (size_t)(rb * 32 + r) * istride + cb * 32 + c4;
  float4 v = *(const float4*)&in[idx];
  if (in2) {
    float4 u = *(const float4*)&in2[idx];
    v.x += u.x; v.y += u.y; v.z += u.z; v.w += u.w;
  }
  *(float4*)&tile[r][c4] = v;
  __syncthreads();
  const int orow = r, oc4 = c4;
  u32x2 pr;
  pr[0] = pk2(tile[oc4 + 0][orow], tile[oc4 + 1][orow]);
  pr[1] = pk2(tile[oc4 + 2][orow], tile[oc4 + 3][orow]);
  *(u32x2*)&out[(size_t)(cb * 32 + orow) * R + rb * 32 + oc4] = pr;
}

// ---------------- RMSNorm + RoPE, fp32 dual-partial input (K path) ------------
__global__ __launch_bounds__(256) void norm_rope(const float* __restrict__ in,
                                                 const float* __restrict__ in2,
                                                 int in_stride, int nheads,
                                                 const float* __restrict__ nw,
                                                 const float* __restrict__ cosT,
                                                 const float* __restrict__ sinT,
                                                 u16* __restrict__ outp, int out_stride,
                                                 float oscale) {
  const int wid = blockIdx.x * 4 + (threadIdx.x >> 6);
  const int l = threadIdx.x & 63;
  const int s = wid / nheads, h = wid - s * nheads;
  const size_t idx = (size_t)s * in_stride + h * 64 + l;
  const float v = in[idx] + in2[idx];
  float sq = v * v;
#pragma unroll
  for (int off = 32; off; off >>= 1) sq += __shfl_xor(sq, off, 64);
  const float rr = rsqrtf(sq * (1.f / 64.f) + 1e-5f);
  const float vn = v * rr * nw[l];
  const float p = __shfl_xor(vn, 1, 64);
  const int i2 = l >> 1;
  const float c = cosT[(size_t)s * 32 + i2];
  const float sn = sinT[(size_t)s * 32 + i2];
  const float o = ((l & 1) ? fmaf(p, sn, vn * c) : fmaf(-p, sn, vn * c)) * oscale;
  outp[(size_t)s * out_stride + h * 64 + l] = f2bf(o);
}

// ---------------- RMSNorm + RoPE, bf16 single input (Q path) ------------
__global__ __launch_bounds__(256) void norm_rope_q(const u16* __restrict__ in,
                                                   int in_stride, int nheads,
                                                   const float* __restrict__ nw,
                                                   const float* __restrict__ cosT,
                                                   const float* __restrict__ sinT,
                                                   u16* __restrict__ outp, int out_stride,
                                                   float oscale) {
  const int wid = blockIdx.x * 4 + (threadIdx.x >> 6);
  const int l = threadIdx.x & 63;
  const int s = wid / nheads, h = wid - s * nheads;
  const size_t idx = (size_t)s * in_stride + h * 64 + l;
  const float v = bf2f(in[idx]);
  float sq = v * v;
#pragma unroll
  for (int off = 32; off; off >>= 1) sq += __shfl_xor(sq, off, 64);
  const float rr = rsqrtf(sq * (1.f / 64.f) + 1e-5f);
  const float vn = v * rr * nw[l];
  const float p = __shfl_xor(vn, 1, 64);
  const int i2 = l >> 1;
  const float c = cosT[(size_t)s * 32 + i2];
  const float sn = sinT[(size_t)s * 32 + i2];
  const float o = ((l & 1) ? fmaf(p, sn, vn * c) : fmaf(-p, sn, vn * c)) * oscale;
  outp[(size_t)s * out_stride + h * 64 + l] = f2bf(o);
}

// ---------------- KV projection: 128x128 tiles, split-K=2 ----------------
__global__ __launch_bounds__(256) void gemm_kv(const u16* __restrict__ A,
                                               const u16* __restrict__ Bt,
                                               float* __restrict__ C0,
                                               float* __restrict__ C1,
                                               int M, int N, int K) {
  __shared__ __align__(16) u16 As[128 * 32];
  __shared__ __align__(16) u16 Bs[128 * 32];
  int bid = blockIdx.x;
  const int cpx = gridDim.x >> 3;
  bid = (bid & 7) * cpx + (bid >> 3);
  const int nbn = N >> 7;
  const int pertile = (M >> 7) * nbn;
  const int sl = bid / pertile;
  const int rem = bid - sl * pertile;
  const int bm = rem / nbn, bn = rem % nbn;
  const int m0 = bm << 7, n0 = bn << 7;
  const int tid = threadIdx.x;
  const int w = tid >> 6, l = tid & 63;
  const int wr = w >> 1, wc = w & 1;
  f32x4 acc[4][4] = {};

  const int Khalf = K >> 1;
  const int kbase = sl * Khalf;

  const char* Ag = (const char*)A +
      ((size_t)(m0 + w * 32 + (l >> 2)) * K + kbase + (l & 3) * 8) * 2;
  const char* Bg = (const char*)Bt +
      ((size_t)(n0 + w * 32 + (l >> 2)) * K + kbase + (l & 3) * 8) * 2;
  char* Al = (char*)As + (w * 32) * 64;
  char* Bl = (char*)Bs + (w * 32) * 64;
  const size_t rowadv = (size_t)16 * K * 2;

  for (int k0 = 0; k0 < Khalf; k0 += 32) {
    gll16(Ag, Al);
    gll16(Ag + rowadv, Al + 1024);
    gll16(Bg, Bl);
    gll16(Bg + rowadv, Bl + 1024);
    Ag += 64; Bg += 64;
    __syncthreads();
    bf16x8 af[4], bq[4];
#pragma unroll
    for (int i = 0; i < 4; ++i) {
      af[i] = *(const bf16x8*)&As[(wr * 64 + i * 16 + (l & 15)) * 32 + (l >> 4) * 8];
      bq[i] = *(const bf16x8*)&Bs[(wc * 64 + i * 16 + (l & 15)) * 32 + (l >> 4) * 8];
    }
#pragma unroll
    for (int mi = 0; mi < 4; ++mi)
#pragma unroll
      for (int ni = 0; ni < 4; ++ni)
        acc[mi][ni] = __builtin_amdgcn_mfma_f32_16x16x32_bf16(af[mi], bq[ni], acc[mi][ni], 0, 0, 0);
    __syncthreads();
  }
  float* Cs = sl ? C1 : C0;
  const int r0 = (l >> 4) * 4, c0 = l & 15;
#pragma unroll
  for (int mi = 0; mi < 4; ++mi)
#pragma unroll
    for (int ni = 0; ni < 4; ++ni)
#pragma unroll
      for (int r = 0; r < 4; ++r)
        Cs[(size_t)(m0 + wr * 64 + mi * 16 + r0 + r) * N + (n0 + wc * 64 + ni * 16 + c0)] =
            acc[mi][ni][r];
}

// ---------------- big GEMM: 256(M) x 128(N) tile, FULL-K, 8 waves (4Mx2N, 64x64/wave)
// Grid = (M/256)*(N/128) = 256 blocks exactly (one round). LDS 96KB = 4 pages x 24KB;
// page = 32-k slice { A 16KB (256 m) | B 8KB (128 n) }. Depth-3 prefetch, 3 loads/page,
// steady vmcnt(6). 128B LDS rows pack two rows' 64B k-slices; 16B slots XOR-swizzled.
template <int BF16OUT>
__global__ __launch_bounds__(512, 2) void gemm_mn(const u16* __restrict__ A,
                                                  const u16* __restrict__ Bt,
                                                  void* __restrict__ Cout,
                                                  int M, int N, int K) {
  extern __shared__ __align__(16) char lds[];
  int bid = blockIdx.x;
  const int cpx = gridDim.x >> 3;
  bid = (bid & 7) * cpx + (bid >> 3);
  const int nbn = N >> 7;
  const int bm = bid / nbn, bn = bid % nbn;
  const int m0 = bm << 8, n0 = bn << 7;
  const int t = threadIdx.x, w = t >> 6, l = t & 63;
  const int wr = w >> 1, wc = w & 1;            // waves 4(M) x 2(N); per-wave 64x64
  const int lr = l & 15, lg = l >> 4;

  const int sR = t >> 3, slot = t & 7;
  const int su = slot ^ (sR & 7);
  const int d1 = sR * 128 + slot * 16;
  const u16* Ag = A + (size_t)(m0 + 2 * sR + (su >> 2)) * K + (su & 3) * 8;
  const u16* Bg = Bt + (size_t)(n0 + 2 * sR + (su >> 2)) * K + (su & 3) * 8;
  const size_t r128 = (size_t)128 * K;

  f32x4 acc[4][4] = {};
  const int NPH = K >> 5;

  auto stage = [&](int ph) {
    const int kofs = ph * 32;
    char* pb = lds + (ph & 3) * 24576;
    gll16(Ag + kofs, pb + d1);                 // A m 0..127
    gll16(Ag + r128 + kofs, pb + 8192 + d1);   // A m 128..255
    gll16(Bg + kofs, pb + 16384 + d1);         // B n 0..127
  };
  stage(0);
  stage(1);
  stage(2);

  const int sfrag = ((lr & 1) << 2) | lg;
  const int swz = (sfrag ^ ((lr >> 1) & 7)) << 4;
  const int aoff = (wr * 32 + (lr >> 1)) * 128 + swz;
  const int boff = 16384 + (wc * 32 + (lr >> 1)) * 128 + swz;

  auto compute = [&](int ph) {
    const char* base = lds + (ph & 3) * 24576;
    bf16x8 a[4], b[4];
#pragma unroll
    for (int mf = 0; mf < 4; ++mf) a[mf] = *(const bf16x8*)(base + aoff + mf * 1024);
#pragma unroll
    for (int nf = 0; nf < 4; ++nf) b[nf] = *(const bf16x8*)(base + boff + nf * 1024);
    __builtin_amdgcn_s_setprio(1);
#pragma unroll
    for (int mf = 0; mf < 4; ++mf)
#pragma unroll
      for (int nf = 0; nf < 4; ++nf)
        acc[mf][nf] = __builtin_amdgcn_mfma_f32_16x16x32_bf16(a[mf], b[nf], acc[mf][nf], 0, 0, 0);
    __builtin_amdgcn_s_setprio(0);
    asm volatile("" ::: "memory");
  };

#pragma unroll 4
  for (int ph = 0; ph < NPH - 3; ++ph) {
    __builtin_amdgcn_sched_barrier(0);
    asm volatile("s_waitcnt vmcnt(6)" ::: "memory");
    __builtin_amdgcn_s_barrier();
    stage(ph + 3);
    compute(ph);
  }
  __builtin_amdgcn_sched_barrier(0);
  asm volatile("s_waitcnt vmcnt(6)" ::: "memory");
  __builtin_amdgcn_s_barrier();
  compute(NPH - 3);
  __builtin_amdgcn_sched_barrier(0);
  asm volatile("s_waitcnt vmcnt(3)" ::: "memory");
  __builtin_amdgcn_s_barrier();
  compute(NPH - 2);
  __builtin_amdgcn_sched_barrier(0);
  asm volatile("s_waitcnt vmcnt(0)" ::: "memory");
  __builtin_amdgcn_s_barrier();
  compute(NPH - 1);

#pragma unroll
  for (int mf = 0; mf < 4; ++mf)
#pragma unroll
    for (int nf = 0; nf < 4; ++nf)
#pragma unroll
      for (int rr = 0; rr < 4; ++rr) {
        const size_t cidx = (size_t)(m0 + wr * 64 + mf * 16 + lg * 4 + rr) * N +
                            (n0 + wc * 64 + nf * 16 + lr);
        if (BF16OUT)
          ((u16*)Cout)[cidx] = bfc(acc[mf][nf][rr]);
        else
          ((float*)Cout)[cidx] = acc[mf][nf][rr];
      }
}

// ---------------- flash attention (causal, GQA), swapped-QK^T, STATIC-max softmax.
// RMSNorm bounds |S*log2e| <= 11.6 -> P = exp2(S) directly (no running max, no
// subtract, no rescale). Q pre-scaled by 0.125*log2(e). LDS addresses hoisted to
// 4 lane-constant bases + compile-time offsets.
__global__ __launch_bounds__(256) void attn_fwd(const u16* __restrict__ Q,
                                                const u16* __restrict__ Kb,
                                                const u16* __restrict__ VT,
                                                u16* __restrict__ O) {
  const int h = blockIdx.x & 63;
  const int qb = (S_LEN / 64 - 1) - (blockIdx.x >> 6);  // big blocks first
  const int kvh = h >> 4;
  __shared__ __align__(16) char KV[2 * 16384];  // page: K 8KB | V 8KB
  const int tid = threadIdx.x;
  const int w = tid >> 6, l = tid & 63;
  const int lr = l & 15, lg = l >> 4;

  const int srow = w * 16 + (l >> 3);
  const int s0 = (l & 7) ^ (srow & 7);                          // inverse bank swizzle
  const int sv = (s0 & 4) | ((s0 & 1) << 1) | ((s0 & 2) >> 1);  // + pi for V packs
  const char* Kg = (const char*)Kb + kvh * 128 + (size_t)srow * 512 + s0 * 16;
  const char* Vg = (const char*)VT + (size_t)(kvh * 64 + srow) * (S_LEN * 2) + sv * 16;
  const int wofs = w * 2048;

  auto stage = [&](int page) {
    char* pb = KV + page * 16384 + wofs;
    gll16(Kg, pb);
    gll16(Kg + 8 * 512, pb + 1024);
    gll16(Vg, pb + 8192);
    gll16(Vg + 8 * (S_LEN * 2), pb + 8192 + 1024);
    Kg += 64 * 512;
    Vg += 128;
  };

  bf16x8 qf[2];
  {
    const size_t qoff = (size_t)(qb * 64 + w * 16 + lr) * DMODEL + h * HD + lg * 8;
    qf[0] = *(const bf16x8*)&Q[qoff];
    qf[1] = *(const bf16x8*)&Q[qoff + 32];
  }
  f32x4 o[4] = {};
  float lrow = 0.f;
  const int qlane = qb * 64 + w * 16 + lr;          // this lane's softmax q-row
  const int abase = (l & 48) | ((l >> 2) & 12);     // lane holding q = lg*4+r is abase+r

  // hoisted LDS fragment base offsets (within a page); ni adds 2048*ni (imm offset)
  const int xr = lr & 7;
  const int kb0 = lr * 128 + ((lg ^ xr) << 4);
  const int kb1 = lr * 128 + (((4 + lg) ^ xr) << 4);
  const int vb0 = 8192 + kb0;
  const int vb1 = 8192 + kb1;

  stage(0);

  for (int t = 0; t <= qb; ++t) {
    __builtin_amdgcn_sched_barrier(0);
    asm volatile("s_waitcnt vmcnt(0)" ::: "memory");
    __builtin_amdgcn_s_barrier();
    __builtin_amdgcn_sched_barrier(0);
    if (t < qb) stage((t + 1) & 1);
    const char* page = KV + (t & 1) * 16384;

    // S^T = K @ Q^T : lane holds S[q=lr][kv = t*64 + ni*16 + lg*4 + r]
    f32x4 sf[4] = {};
#pragma unroll
    for (int ni = 0; ni < 4; ++ni) {
      bf16x8 kf0 = *(const bf16x8*)(page + kb0 + ni * 2048);
      bf16x8 kf1 = *(const bf16x8*)(page + kb1 + ni * 2048);
      sf[ni] = __builtin_amdgcn_mfma_f32_16x16x32_bf16(kf0, qf[0], sf[ni], 0, 0, 0);
      sf[ni] = __builtin_amdgcn_mfma_f32_16x16x32_bf16(kf1, qf[1], sf[ni], 0, 0, 0);
    }
    if (t == qb) {
      const int kvb = t * 64 + lg * 4;
#pragma unroll
      for (int ni = 0; ni < 4; ++ni)
#pragma unroll
        for (int r = 0; r < 4; ++r)
          if (kvb + ni * 16 + r > qlane) sf[ni][r] = -1e30f;
    }
    // static-max softmax: P = exp2(S), bounded by 2^11.6
    float p[4][4];
    float r4[4];
#pragma unroll
    for (int ni = 0; ni < 4; ++ni) {
#pragma unroll
      for (int r = 0; r < 4; ++r) p[ni][r] = ex2(sf[ni][r]);
      r4[ni] = (p[ni][0] + p[ni][1]) + (p[ni][2] + p[ni][3]);
    }
    float rs = (r4[0] + r4[1]) + (r4[2] + r4[3]);
    rs += __shfl_xor(rs, 16, 64);
    rs += __shfl_xor(rs, 32, 64);
    lrow += rs;

    // O += P @ V : build A-fragments in-register (packs + xor16 exchange)
    const bool odd = (lg & 1);
#pragma unroll
    for (int kk = 0; kk < 2; ++kk) {
      const int nA = 2 * kk, nB = 2 * kk + 1;
      const u32 cA0 = pk2(p[nA][0], p[nA][1]), cA1 = pk2(p[nA][2], p[nA][3]);
      const u32 cB0 = pk2(p[nB][0], p[nB][1]), cB1 = pk2(p[nB][2], p[nB][3]);
      const u32 cS0 = odd ? cB0 : cA0, cS1 = odd ? cB1 : cA1;
      const u32 cP0 = odd ? cA0 : cB0, cP1 = odd ? cA1 : cB1;
      const u32 rP0 = (u32)__shfl_xor((int)cP0, 16, 64);
      const u32 rP1 = (u32)__shfl_xor((int)cP1, 16, 64);
      u32x4 wv;
      wv[0] = odd ? rP0 : cS0;
      wv[1] = odd ? rP1 : cS1;
      wv[2] = odd ? cS0 : rP0;
      wv[3] = odd ? cS1 : rP1;
      const bf16x8 pa = __builtin_bit_cast(bf16x8, wv);
      const int vb = kk ? vb1 : vb0;
#pragma unroll
      for (int ni = 0; ni < 4; ++ni) {
        bf16x8 vf = *(const bf16x8*)(page + vb + ni * 2048);
        o[ni] = __builtin_amdgcn_mfma_f32_16x16x32_bf16(pa, vf, o[ni], 0, 0, 0);
      }
    }
  }
  const float lv0 = __shfl(lrow, abase + 0, 64);
  const float lv1 = __shfl(lrow, abase + 1, 64);
  const float lv2 = __shfl(lrow, abase + 2, 64);
  const float lv3 = __shfl(lrow, abase + 3, 64);
  const f32x4 lv = {lv0, lv1, lv2, lv3};
#pragma unroll
  for (int ni = 0; ni < 4; ++ni)
#pragma unroll
    for (int r = 0; r < 4; ++r) {
      const size_t orow = (size_t)(qb * 64 + w * 16 + lg * 4 + r);
      O[orow * DMODEL + h * HD + ni * 16 + lr] = f2bf(o[ni][r] / lv[r]);
    }
}

// ---------------- launcher ----------------
extern "C" void kernel_launch(void* const* d_in, const int* in_sizes, int n_in,
                              void* d_out, int out_size, void* d_ws, size_t ws_size,
                              hipStream_t stream) {
  const float* x   = (const float*)d_in[0];
  const float* wq  = (const float*)d_in[1];
  const float* wk  = (const float*)d_in[2];
  const float* wv  = (const float*)d_in[3];
  const float* wo  = (const float*)d_in[4];
  const float* qnw = (const float*)d_in[5];
  const float* knw = (const float*)d_in[6];
  const float* fc  = (const float*)d_in[7];
  const float* fs  = (const float*)d_in[8];
  float* out = (float*)d_out;

  char* ws = (char*)d_ws;
  size_t off = 0;
  auto alloc = [&](size_t bytes) {
    char* p = ws + off;
    off += (bytes + 255) & ~(size_t)255;
    return p;
  };
  u16*   xb    = (u16*)alloc((size_t)S_LEN * DMODEL * 2);
  u16*   wqT   = (u16*)alloc((size_t)DMODEL * DMODEL * 2);
  u16*   wkvT  = (u16*)alloc((size_t)512 * DMODEL * 2);
  u16*   woT   = (u16*)alloc((size_t)DMODEL * DMODEL * 2);
  u16*   Pq    = (u16*)alloc((size_t)S_LEN * DMODEL * 2);
  float* KV0   = (float*)alloc((size_t)S_LEN * 512 * 4);
  float* KV1   = (float*)alloc((size_t)S_LEN * 512 * 4);
  u16*   Qn    = (u16*)alloc((size_t)S_LEN * DMODEL * 2);
  u16*   Kn    = (u16*)alloc((size_t)S_LEN * 256 * 2);
  u16*   VTb   = (u16*)alloc((size_t)256 * S_LEN * 2);
  u16*   Ob    = (u16*)alloc((size_t)S_LEN * DMODEL * 2);

  hipFuncSetAttribute((const void*)gemm_mn<1>, hipFuncAttributeMaxDynamicSharedMemorySize, 98304);
  hipFuncSetAttribute((const void*)gemm_mn<0>, hipFuncAttributeMaxDynamicSharedMemorySize, 98304);

  cvt_f32_bf16_v4<<<(S_LEN * DMODEL / 4) / 256, 256, 0, stream>>>(x, xb);
  tconvs<<<(4096 / 32) * (4096 / 32), 256, 0, stream>>>(wq, nullptr, 4096, wqT, 4096, 4096);
  tconvs<<<(4096 / 32) * (256 / 32), 256, 0, stream>>>(wk, nullptr, 256, wkvT, 4096, 256);
  tconvs<<<(4096 / 32) * (256 / 32), 256, 0, stream>>>(wv, nullptr, 256,
      wkvT + (size_t)256 * 4096, 4096, 256);
  tconvs<<<(4096 / 32) * (4096 / 32), 256, 0, stream>>>(wo, nullptr, 4096, woT, 4096, 4096);

  // Q projection: full-K 256x128 tiles -> 8*32 = 256 blocks, bf16 output
  gemm_mn<1><<<(2048 / 256) * (4096 / 128), 512, 98304, stream>>>(
      xb, wqT, Pq, 2048, 4096, 4096);
  // KV projection: split-K2, 128 blocks, fp32 partials
  gemm_kv<<<2 * (2048 / 128) * (512 / 128), 256, 0, stream>>>(
      xb, wkvT, KV0, KV1, 2048, 512, 4096);

  const float QSCALE = 0.125f * 1.44269504088896340736f;
  norm_rope_q<<<(S_LEN * NH) / 4, 256, 0, stream>>>(Pq, DMODEL, NH, qnw, fc, fs,
                                                    Qn, DMODEL, QSCALE);
  norm_rope<<<(S_LEN * NKV) / 4, 256, 0, stream>>>(KV0, KV1, 512, NKV,
                                                   knw, fc, fs, Kn, 256, 1.0f);
  // V^T: V partials (2048 x 256, row stride 512) -> VT (256 x 2048 bf16)
  tconvs<<<(2048 / 32) * (256 / 32), 256, 0, stream>>>(KV0 + 256, KV1 + 256, 512,
                                                       VTb, 2048, 256);

  attn_fwd<<<(S_LEN / 64) * NH, 256, 0, stream>>>(Qn, Kn, VTb, Ob);

  // out projection: full-K 256x128 tiles -> 256 blocks, fp32 direct to out
  gemm_mn<0><<<(2048 / 256) * (4096 / 128), 512, 98304, stream>>>(
      Ob, woT, out, 2048, 4096, 4096);
}